// Round 1
// baseline (619.260 us; speedup 1.0000x reference)
//
#include <hip/hip_runtime.h>
#include <hip/hip_bf16.h>

// ---------------- types / helpers ----------------
typedef __attribute__((ext_vector_type(8))) __bf16 bf16x8;
typedef __attribute__((ext_vector_type(4))) float f32x4;
typedef __attribute__((ext_vector_type(4))) unsigned int u32x4;
typedef __attribute__((ext_vector_type(4))) unsigned short u16x4;

#define MFMA16(a,b,c) __builtin_amdgcn_mfma_f32_16x16x32_bf16((a),(b),(c),0,0,0)

__device__ __forceinline__ float b2f(unsigned short u) {
  union { unsigned int i; float f; } v; v.i = ((unsigned int)u) << 16; return v.f;
}
__device__ __forceinline__ unsigned short f2b(float f) {
  union { float f; unsigned int u; } v; v.f = f;
  unsigned int u = v.u;
  unsigned int r = (u + 0x7fffu + ((u >> 16) & 1u)) >> 16;  // RTNE
  return (unsigned short)r;
}

#define NIMG 16
#define CIN  256
#define CD   64
#define HH   96
#define WW   96
#define HW   (HH*WW)          // 9216

// ---------------- workspace byte offsets ----------------
#define OFF_Y1   (0ll)          // bf16 16*64*9216           = 18,874,368 B
#define OFF_Y2   (18874368ll)   // bf16 same
#define OFF_OFF  (37748736ll)   // f32  16*18*9216           = 10,616,832 B
#define OFF_MOD  (48365568ll)   // f32  16*9*9216            =  5,308,416 B
#define OFF_M    (53673984ll)   // f32  16*10*9216           =  5,898,240 B
#define OFF_NP   (59572224ll)   // f32  16*8*10*64           =    327,680 B
#define OFF_DP   (59899904ll)   // f32  16*8*16              =      8,192 B
#define OFF_SBN  (59908096ll)   // f32  64
#define OFF_TBN  (59908352ll)   // f32  64
#define OFF_W1   (59908608ll)   // bf16 9*32*64*8 = 147456   =    294,912 B
#define OFF_W2   (60203520ll)   // bf16 9*8*32*8  = 18432    =     36,864 B
#define OFF_W3   (60240384ll)   // bf16 9*8*64*8  = 36864    =     73,728 B
#define WS_NEEDED (60314112ll)

// ---------------- prep: weight repack (frag-order, bf16) + BN fold ----------------
// w1 layout: [t][cg(32)][o(64)][j(8)]  (c = cg*8+j, K-chunk staging is linear copy)
// w2 layout: [t][cg(8)][o(32)][j(8)]   (o<18 -> off_w, 18..26 -> mod_w, else 0)
// w3 layout: [t][cg(8)][o(64)][j(8)]
__global__ void k_prep(const float* __restrict__ conv1_w, const float* __restrict__ conv1_b,
                       const float* __restrict__ bn_gamma, const float* __restrict__ bn_beta,
                       const float* __restrict__ bn_mean, const float* __restrict__ bn_var,
                       const float* __restrict__ off_w, const float* __restrict__ mod_w,
                       const float* __restrict__ dcn_w,
                       unsigned short* __restrict__ w1, unsigned short* __restrict__ w2,
                       unsigned short* __restrict__ w3,
                       float* __restrict__ sbn, float* __restrict__ tbn)
{
  int e = blockIdx.x * 256 + threadIdx.x;
  if (e < 147456) {
    int j = e & 7, o = (e >> 3) & 63, cg = (e >> 9) & 31, t = e >> 14;
    w1[e] = f2b(conv1_w[(o * 256 + cg * 8 + j) * 9 + t]);
  } else if (e < 147456 + 18432) {
    int i = e - 147456;
    int j = i & 7, o = (i >> 3) & 31, cg = (i >> 8) & 7, t = i >> 11;
    int ch = cg * 8 + j;
    float v = 0.f;
    if (o < 18)      v = off_w[(o * 64 + ch) * 9 + t];
    else if (o < 27) v = mod_w[((o - 18) * 64 + ch) * 9 + t];
    w2[i] = f2b(v);
  } else if (e < 147456 + 18432 + 36864) {
    int i = e - 147456 - 18432;
    int j = i & 7, o = (i >> 3) & 63, cg = (i >> 9) & 7, t = i >> 12;
    w3[i] = f2b(dcn_w[(o * 64 + cg * 8 + j) * 9 + t]);
  } else {
    int i = e - (147456 + 18432 + 36864);
    if (i < 64) {
      sbn[i] = bn_gamma[i] * rsqrtf(bn_var[i] + 1e-5f);
    } else if (i < 128) {
      int q = i - 64;
      float s = bn_gamma[q] * rsqrtf(bn_var[q] + 1e-5f);
      tbn[q] = (conv1_b[q] - bn_mean[q]) * s + bn_beta[q];
    }
  }
}

// ---------------- conv1 (256->64) + BN + ReLU, MFMA bf16 ----------------
// block: 256 thr (4 waves), 2 output rows x 64 ch x 96 px. grid (48, 16).
// wave: (row = wv&1, ch-half = wv>>1): 2 ch-tiles x 6 w-tiles.
__global__ __launch_bounds__(256)
void k_conv1(const float* __restrict__ x, const unsigned short* __restrict__ w1,
             const float* __restrict__ sbn, const float* __restrict__ tbn,
             unsigned short* __restrict__ y1)
{
  __shared__ unsigned short xs[4][98][48];   // [r][wp][c]  c-stride 48 (96B)
  __shared__ unsigned short As[9 * 4 * 64 * 8];

  const int tid = threadIdx.x;
  const int lane = tid & 63, wv = tid >> 6;
  const int l16 = lane & 15, lg = lane >> 4;
  const int wrow = wv & 1, wch = wv >> 1;
  const int h0 = blockIdx.x * 2;
  const int n = blockIdx.y;
  const float* xn = x + (size_t)n * CIN * HW;

  f32x4 acc[2][6];
  #pragma unroll
  for (int a = 0; a < 2; ++a)
    #pragma unroll
    for (int b = 0; b < 6; ++b) { f32x4 z = {0.f,0.f,0.f,0.f}; acc[a][b] = z; }

  for (int chunk = 0; chunk < 8; ++chunk) {
    const int c0 = chunk * 32;
    __syncthreads();
    // stage x chunk: 32c x 4r x 96w (f32 -> bf16), transposed to [r][wp][c]
    #pragma unroll
    for (int it = 0; it < 12; ++it) {
      int idx = tid + it * 256;              // < 3072
      int c = idx & 31;
      int w4 = (idx >> 5) % 24;
      int r = idx / 768;
      int row = h0 - 1 + r;
      f32x4 v = {0.f,0.f,0.f,0.f};
      if (row >= 0 && row < HH)
        v = *reinterpret_cast<const f32x4*>(xn + (c0 + c) * HW + row * WW + w4 * 4);
      int wp = w4 * 4 + 1;
      xs[r][wp + 0][c] = f2b(v[0]);
      xs[r][wp + 1][c] = f2b(v[1]);
      xs[r][wp + 2][c] = f2b(v[2]);
      xs[r][wp + 3][c] = f2b(v[3]);
      if (w4 == 0)  xs[r][0][c]  = 0;
      if (w4 == 23) xs[r][97][c] = 0;
    }
    // stage A chunk (linear coalesced copy, already frag-order)
    #pragma unroll
    for (int it = 0; it < 9; ++it) {
      int idx = tid + it * 256;              // < 2304
      int o = idx & 63, g = (idx >> 6) & 3, t = idx >> 8;
      *reinterpret_cast<u32x4*>(&As[((t * 4 + g) * 64 + o) * 8]) =
        *reinterpret_cast<const u32x4*>(&w1[((t * 32 + chunk * 4 + g) * 64 + o) * 8]);
    }
    __syncthreads();
    #pragma unroll
    for (int t = 0; t < 9; ++t) {
      const int ky = t / 3, kx = t % 3;
      bf16x8 a0 = *reinterpret_cast<const bf16x8*>(&As[((t*4 + lg)*64 + wch*32 + l16)*8]);
      bf16x8 a1 = *reinterpret_cast<const bf16x8*>(&As[((t*4 + lg)*64 + wch*32 + 16 + l16)*8]);
      const int r = wrow + ky;
      #pragma unroll
      for (int wt = 0; wt < 6; ++wt) {
        bf16x8 b = *reinterpret_cast<const bf16x8*>(&xs[r][wt*16 + l16 + kx][lg*8]);
        acc[0][wt] = MFMA16(a0, b, acc[0][wt]);
        acc[1][wt] = MFMA16(a1, b, acc[1][wt]);
      }
    }
  }
  // epilogue: BN + ReLU, store bf16
  const int h = h0 + wrow;
  #pragma unroll
  for (int ct = 0; ct < 2; ++ct) {
    #pragma unroll
    for (int j = 0; j < 4; ++j) {
      int o = wch * 32 + ct * 16 + lg * 4 + j;
      float s = sbn[o], tt = tbn[o];
      #pragma unroll
      for (int wt = 0; wt < 6; ++wt) {
        float v = acc[ct][wt][j] * s + tt;
        v = v > 0.f ? v : 0.f;
        y1[((n * CD + o) * HH + h) * WW + wt * 16 + l16] = f2b(v);
      }
    }
  }
}

// ---------------- off/mod conv (64 -> 18+9), MFMA bf16 ----------------
// grid (48,16). wave: (row = wv&1, o-tile = wv>>1).
__global__ __launch_bounds__(256)
void k_conv2(const unsigned short* __restrict__ y1, const unsigned short* __restrict__ w2,
             const float* __restrict__ off_b, const float* __restrict__ mod_b,
             float* __restrict__ off_o, float* __restrict__ mod_o)
{
  __shared__ unsigned short xs[4][98][48];
  __shared__ unsigned short As[9 * 4 * 32 * 8];

  const int tid = threadIdx.x;
  const int lane = tid & 63, wv = tid >> 6;
  const int l16 = lane & 15, lg = lane >> 4;
  const int wrow = wv & 1, wct = wv >> 1;
  const int h0 = blockIdx.x * 2;
  const int n = blockIdx.y;
  const unsigned short* y1n = y1 + (size_t)n * CD * HW;

  f32x4 acc[6];
  #pragma unroll
  for (int b = 0; b < 6; ++b) { f32x4 z = {0.f,0.f,0.f,0.f}; acc[b] = z; }

  for (int chunk = 0; chunk < 2; ++chunk) {
    const int c0 = chunk * 32;
    __syncthreads();
    // stage y1 chunk (bf16 already): 32c x 4r x 96w
    #pragma unroll
    for (int it = 0; it < 6; ++it) {
      int idx = tid + it * 256;             // < 1536
      int c = idx & 31;
      int w8 = (idx >> 5) % 12;
      int r = idx / 384;
      int row = h0 - 1 + r;
      u32x4 v = {0u,0u,0u,0u};
      if (row >= 0 && row < HH)
        v = *reinterpret_cast<const u32x4*>(y1n + (c0 + c) * HW + row * WW + w8 * 8);
      int wp = w8 * 8 + 1;
      #pragma unroll
      for (int q = 0; q < 4; ++q) {
        unsigned int word = v[q];
        xs[r][wp + 2*q + 0][c] = (unsigned short)(word & 0xffffu);
        xs[r][wp + 2*q + 1][c] = (unsigned short)(word >> 16);
      }
      if (w8 == 0)  xs[r][0][c]  = 0;
      if (w8 == 11) xs[r][97][c] = 0;
    }
    // stage A
    #pragma unroll
    for (int it = 0; it < 5; ++it) {
      int idx = tid + it * 256;
      if (idx < 1152) {
        int o = idx & 31, g = (idx >> 5) & 3, t = idx >> 7;
        *reinterpret_cast<u32x4*>(&As[((t * 4 + g) * 32 + o) * 8]) =
          *reinterpret_cast<const u32x4*>(&w2[((t * 8 + chunk * 4 + g) * 32 + o) * 8]);
      }
    }
    __syncthreads();
    #pragma unroll
    for (int t = 0; t < 9; ++t) {
      const int ky = t / 3, kx = t % 3;
      bf16x8 a = *reinterpret_cast<const bf16x8*>(&As[((t*4 + lg)*32 + wct*16 + l16)*8]);
      const int r = wrow + ky;
      #pragma unroll
      for (int wt = 0; wt < 6; ++wt) {
        bf16x8 b = *reinterpret_cast<const bf16x8*>(&xs[r][wt*16 + l16 + kx][lg*8]);
        acc[wt] = MFMA16(a, b, acc[wt]);
      }
    }
  }
  const int h = h0 + wrow;
  #pragma unroll
  for (int j = 0; j < 4; ++j) {
    int o = wct * 16 + lg * 4 + j;
    if (o < 18) {
      float bo = off_b[o];
      #pragma unroll
      for (int wt = 0; wt < 6; ++wt)
        off_o[((n * 18 + o) * HH + h) * WW + wt * 16 + l16] = acc[wt][j] + bo;
    } else if (o < 27) {
      int q = o - 18;
      float bo = mod_b[q];
      #pragma unroll
      for (int wt = 0; wt < 6; ++wt) {
        float v = acc[wt][j] + bo;
        mod_o[((n * 9 + q) * HH + h) * WW + wt * 16 + l16] = 2.f / (1.f + expf(-v));
      }
    }
  }
}

// ---------------- deformable conv (DCNv2), MFMA bf16 ----------------
// grid (96,16): one row per block. meta precomputed per (pix,tap); per-tap gather+GEMM.
__global__ __launch_bounds__(256)
void k_dcn(const unsigned short* __restrict__ y1, const float* __restrict__ off_i,
           const float* __restrict__ mod_i, const unsigned short* __restrict__ w3,
           const float* __restrict__ dcn_b, unsigned short* __restrict__ y2)
{
  __shared__ f32x4 wgt[864];
  __shared__ int ofs[864][4];
  __shared__ unsigned short Bs[96][72];      // [pix][c], stride 144B

  const int tid = threadIdx.x;
  const int lane = tid & 63, wv = tid >> 6;
  const int l16 = lane & 15, lg = lane >> 4;
  const int h = blockIdx.x, n = blockIdx.y;

  // tap metadata: bilinear weights (validity-zeroed, pre-x mod) + clamped offsets
  #pragma unroll
  for (int it = 0; it < 4; ++it) {
    int e = tid + it * 256;
    if (e < 864) {
      int k = e / 96, p = e % 96;
      float dy = off_i[((n * 18 + 2 * k) * HH + h) * WW + p];
      float dx = off_i[((n * 18 + 2 * k + 1) * HH + h) * WW + p];
      float mw = mod_i[((n * 9 + k) * HH + h) * WW + p];
      float py = (float)(h + k / 3 - 1) + dy;
      float px = (float)(p + k % 3 - 1) + dx;
      float y0f = floorf(py), x0f = floorf(px);
      float wy = py - y0f, wx = px - x0f;
      int iy0 = (int)y0f, ix0 = (int)x0f;
      int iy1 = iy0 + 1, ix1 = ix0 + 1;
      float vy0 = (iy0 >= 0 && iy0 < HH) ? 1.f : 0.f;
      float vy1 = (iy1 >= 0 && iy1 < HH) ? 1.f : 0.f;
      float vx0 = (ix0 >= 0 && ix0 < WW) ? 1.f : 0.f;
      float vx1 = (ix1 >= 0 && ix1 < WW) ? 1.f : 0.f;
      f32x4 w4;
      w4[0] = (1.f - wy) * (1.f - wx) * mw * vy0 * vx0;
      w4[1] = (1.f - wy) * wx         * mw * vy0 * vx1;
      w4[2] = wy         * (1.f - wx) * mw * vy1 * vx0;
      w4[3] = wy         * wx         * mw * vy1 * vx1;
      wgt[e] = w4;
      int cy0 = iy0 < 0 ? 0 : (iy0 > 95 ? 95 : iy0);
      int cy1 = iy1 < 0 ? 0 : (iy1 > 95 ? 95 : iy1);
      int cx0 = ix0 < 0 ? 0 : (ix0 > 95 ? 95 : ix0);
      int cx1 = ix1 < 0 ? 0 : (ix1 > 95 ? 95 : ix1);
      ofs[e][0] = cy0 * WW + cx0; ofs[e][1] = cy0 * WW + cx1;
      ofs[e][2] = cy1 * WW + cx0; ofs[e][3] = cy1 * WW + cx1;
    }
  }
  __syncthreads();

  const unsigned short* y1n = y1 + (size_t)n * CD * HW;
  f32x4 acc[6];
  #pragma unroll
  for (int b = 0; b < 6; ++b) { f32x4 z = {0.f,0.f,0.f,0.f}; acc[b] = z; }

  for (int t = 0; t < 9; ++t) {
    // stage B_t: v[c][pix] = mod * bilinear(y1)
    #pragma unroll 4
    for (int it = 0; it < 24; ++it) {
      int idx = tid + it * 256;           // < 6144
      int p = idx % 96, c = idx / 96;
      f32x4 w4 = wgt[t * 96 + p];
      const int* o4 = ofs[t * 96 + p];
      const unsigned short* base = y1n + c * HW;
      float v = w4[0] * b2f(base[o4[0]]) + w4[1] * b2f(base[o4[1]])
              + w4[2] * b2f(base[o4[2]]) + w4[3] * b2f(base[o4[3]]);
      Bs[p][c] = f2b(v);
    }
    __syncthreads();
    #pragma unroll
    for (int kk = 0; kk < 2; ++kk) {
      bf16x8 a = *reinterpret_cast<const bf16x8*>(
          &w3[((t * 8 + kk * 4 + lg) * 64 + wv * 16 + l16) * 8]);
      #pragma unroll
      for (int wt = 0; wt < 6; ++wt) {
        bf16x8 b = *reinterpret_cast<const bf16x8*>(&Bs[wt * 16 + l16][kk * 32 + lg * 8]);
        acc[wt] = MFMA16(a, b, acc[wt]);
      }
    }
    __syncthreads();
  }
  #pragma unroll
  for (int j = 0; j < 4; ++j) {
    int o = wv * 16 + lg * 4 + j;
    float bo = dcn_b[o];
    #pragma unroll
    for (int wt = 0; wt < 6; ++wt)
      y2[((n * CD + o) * HH + h) * WW + wt * 16 + l16] = f2b(acc[wt][j] + bo);
  }
}

// ---------------- mask resize: bilinear x0.5 == 2x2 average ----------------
__global__ void k_resize(const float* __restrict__ masks, float* __restrict__ m)
{
  int gid = blockIdx.x * 256 + threadIdx.x;
  if (gid >= 16 * 10 * HW) return;
  int pix = gid % HW;
  int r = gid / HW;                        // bf*10 + i
  int oh = pix / WW, ow = pix % WW;
  const float* s = masks + ((size_t)r * 192 + 2 * oh) * 192 + 2 * ow;
  m[gid] = 0.25f * (s[0] + s[1] + s[192] + s[193]);
}

// ---------------- pooling partials (f32, deterministic) ----------------
// grid (8 seg, 16 bf). per block: 1152 pixels, all 10 masks x 64 ch.
__global__ __launch_bounds__(256)
void k_pool(const unsigned short* __restrict__ y2, const float* __restrict__ m,
            float* __restrict__ num_part, float* __restrict__ den_part)
{
  __shared__ float ms[10][1152];
  __shared__ float red[4][10][64];
  __shared__ float den_red[10][16];
  const int tid = threadIdx.x;
  const int seg = blockIdx.x, bf = blockIdx.y;
  const int p0 = seg * 1152;

  #pragma unroll
  for (int it = 0; it < 45; ++it) {
    int idx = tid + it * 256;              // < 11520
    int i = idx / 1152, p = idx % 1152;
    ms[i][p] = m[(bf * 10 + i) * HW + p0 + p];
  }
  __syncthreads();

  const int c = tid & 63, grp = tid >> 6;
  float acc[10];
  #pragma unroll
  for (int i = 0; i < 10; ++i) acc[i] = 0.f;
  const unsigned short* yrow = y2 + (size_t)(bf * 64 + c) * HW + p0 + grp * 288;
  for (int qb = 0; qb < 72; ++qb) {
    u16x4 yv = *reinterpret_cast<const u16x4*>(yrow + qb * 4);
    float v0 = b2f(yv[0]), v1 = b2f(yv[1]), v2 = b2f(yv[2]), v3 = b2f(yv[3]);
    int pp = grp * 288 + qb * 4;
    #pragma unroll
    for (int i = 0; i < 10; ++i) {
      f32x4 mv = *reinterpret_cast<const f32x4*>(&ms[i][pp]);
      acc[i] += v0 * mv[0] + v1 * mv[1] + v2 * mv[2] + v3 * mv[3];
    }
  }
  #pragma unroll
  for (int i = 0; i < 10; ++i) red[grp][i][c] = acc[i];
  if (tid < 160) {
    int i = tid >> 4, s16 = tid & 15;
    float s = 0.f;
    for (int k2 = 0; k2 < 72; ++k2) s += ms[i][s16 + k2 * 16];
    den_red[i][s16] = s;
  }
  __syncthreads();
  #pragma unroll
  for (int it = 0; it < 3; ++it) {
    int e = tid + it * 256;
    if (e < 640) {
      int i = e >> 6, cc = e & 63;
      num_part[((bf * 8 + seg) * 10 + i) * 64 + cc] =
        red[0][i][cc] + red[1][i][cc] + red[2][i][cc] + red[3][i][cc];
    }
  }
  if (tid < 10) {
    float s = 0.f;
    for (int k2 = 0; k2 < 16; ++k2) s += den_red[tid][k2];
    den_part[(bf * 8 + seg) * 16 + tid] = s;
  }
}

// ---------------- head: pool-normalize, smooth+ReLU, inc/pix GEMMs (f32) ----------------
__global__ void k_head(const float* __restrict__ num_part, const float* __restrict__ den_part,
                       const float* __restrict__ smooth_w, const float* __restrict__ smooth_b,
                       const float* __restrict__ inc_w, const float* __restrict__ pix_w,
                       float* __restrict__ out)
{
  __shared__ float pool_s[10][64];
  __shared__ float feat_s[10][64];
  const int tid = threadIdx.x;
  const int bf = blockIdx.x;
  #pragma unroll
  for (int it = 0; it < 3; ++it) {
    int e = tid + it * 256;
    if (e < 640) {
      int i = e >> 6, cc = e & 63;
      float nsum = 0.f, dsum = 0.f;
      #pragma unroll
      for (int s = 0; s < 8; ++s) {
        nsum += num_part[((bf * 8 + s) * 10 + i) * 64 + cc];
        dsum += den_part[(bf * 8 + s) * 16 + i];
      }
      pool_s[i][cc] = nsum / (dsum + 1e-6f);
    }
  }
  __syncthreads();
  #pragma unroll
  for (int it = 0; it < 3; ++it) {
    int e = tid + it * 256;
    if (e < 640) {
      int i = e >> 6, cc = e & 63;
      float s = smooth_b[cc];
      for (int k = 0; k < 64; ++k) s += pool_s[i][k] * smooth_w[cc * 64 + k];
      feat_s[i][cc] = s > 0.f ? s : 0.f;
    }
  }
  __syncthreads();
  #pragma unroll
  for (int it = 0; it < 5; ++it) {
    int e = tid + it * 256;
    if (e < 1280) {
      int i = e >> 7, oc = e & 127;
      float s = 0.f;
      for (int k = 0; k < 64; ++k) s += feat_s[i][k] * inc_w[oc * 64 + k];
      out[(bf * 10 + i) * 128 + oc] = s;
    }
  }
  #pragma unroll
  for (int it = 0; it < 3; ++it) {
    int e = tid + it * 256;
    if (e < 640) {
      int i = e >> 6, oc = e & 63;
      float s = 0.f;
      for (int k = 0; k < 64; ++k) s += feat_s[i][k] * pix_w[oc * 64 + k];
      out[20480 + (bf * 10 + i) * 64 + oc] = s;
    }
  }
}

// ---------------- launch ----------------
extern "C" void kernel_launch(void* const* d_in, const int* in_sizes, int n_in,
                              void* d_out, int out_size, void* d_ws, size_t ws_size,
                              hipStream_t stream)
{
  const float* x        = (const float*)d_in[0];
  const float* masks    = (const float*)d_in[1];
  const float* conv1_w  = (const float*)d_in[2];
  const float* conv1_b  = (const float*)d_in[3];
  const float* bn_gamma = (const float*)d_in[4];
  const float* bn_beta  = (const float*)d_in[5];
  const float* bn_mean  = (const float*)d_in[6];
  const float* bn_var   = (const float*)d_in[7];
  const float* off_b    = (const float*)d_in[9];
  const float* mod_b    = (const float*)d_in[11];
  const float* dcn_b    = (const float*)d_in[13];
  const float* smooth_w = (const float*)d_in[14];
  const float* smooth_b = (const float*)d_in[15];
  const float* inc_w    = (const float*)d_in[16];
  const float* pix_w    = (const float*)d_in[17];
  const float* off_w    = (const float*)d_in[8];
  const float* mod_w    = (const float*)d_in[10];
  const float* dcn_w    = (const float*)d_in[12];
  float* out = (float*)d_out;

  if (ws_size < (size_t)WS_NEEDED) return;  // loud failure (wrong output) rather than OOB
  char* ws = (char*)d_ws;
  unsigned short* y1  = (unsigned short*)(ws + OFF_Y1);
  unsigned short* y2  = (unsigned short*)(ws + OFF_Y2);
  float* off_t        = (float*)(ws + OFF_OFF);
  float* mod_t        = (float*)(ws + OFF_MOD);
  float* mbuf         = (float*)(ws + OFF_M);
  float* num_part     = (float*)(ws + OFF_NP);
  float* den_part     = (float*)(ws + OFF_DP);
  float* sbn          = (float*)(ws + OFF_SBN);
  float* tbn          = (float*)(ws + OFF_TBN);
  unsigned short* w1  = (unsigned short*)(ws + OFF_W1);
  unsigned short* w2  = (unsigned short*)(ws + OFF_W2);
  unsigned short* w3  = (unsigned short*)(ws + OFF_W3);

  k_prep<<<793, 256, 0, stream>>>(conv1_w, conv1_b, bn_gamma, bn_beta, bn_mean, bn_var,
                                  off_w, mod_w, dcn_w, w1, w2, w3, sbn, tbn);
  k_conv1<<<dim3(48, 16), 256, 0, stream>>>(x, w1, sbn, tbn, y1);
  k_conv2<<<dim3(48, 16), 256, 0, stream>>>(y1, w2, off_b, mod_b, off_t, mod_t);
  k_dcn<<<dim3(96, 16), 256, 0, stream>>>(y1, off_t, mod_t, w3, dcn_b, y2);
  k_resize<<<(16 * 10 * HW + 255) / 256, 256, 0, stream>>>(masks, mbuf);
  k_pool<<<dim3(8, 16), 256, 0, stream>>>(y2, mbuf, num_part, den_part);
  k_head<<<16, 256, 0, stream>>>(num_part, den_part, smooth_w, smooth_b, inc_w, pix_w, out);
}

// Round 2
// 509.934 us; speedup vs baseline: 1.2144x; 1.2144x over previous
//
#include <hip/hip_runtime.h>
#include <hip/hip_bf16.h>

// ---------------- types / helpers ----------------
typedef __attribute__((ext_vector_type(8))) __bf16 bf16x8;
typedef __attribute__((ext_vector_type(4))) float f32x4;
typedef __attribute__((ext_vector_type(4))) unsigned int u32x4;
typedef __attribute__((ext_vector_type(4))) unsigned short u16x4;
typedef __attribute__((ext_vector_type(8))) unsigned short ushort8;
typedef __attribute__((ext_vector_type(4))) int i32x4;

#define MFMA16(a,b,c) __builtin_amdgcn_mfma_f32_16x16x32_bf16((a),(b),(c),0,0,0)

__device__ __forceinline__ float b2f(unsigned short u) {
  union { unsigned int i; float f; } v; v.i = ((unsigned int)u) << 16; return v.f;
}
__device__ __forceinline__ unsigned short f2b(float f) {
  union { float f; unsigned int u; } v; v.f = f;
  unsigned int u = v.u;
  unsigned int r = (u + 0x7fffu + ((u >> 16) & 1u)) >> 16;  // RTNE
  return (unsigned short)r;
}

#define NIMG 16
#define CIN  256
#define CD   64
#define HH   96
#define WW   96
#define HW   (HH*WW)          // 9216

// ---------------- workspace byte offsets ----------------
#define OFF_Y1   (0ll)          // bf16 NHWC 16*9216*64      = 18,874,368 B
#define OFF_Y2   (18874368ll)   // bf16 NCHW same size
#define OFF_OFF  (37748736ll)   // f32  16*18*9216           = 10,616,832 B (reused by pool partials)
#define OFF_MOD  (48365568ll)   // f32  16*9*9216            =  5,308,416 B
#define OFF_M    (53673984ll)   // f32  16*10*9216           =  5,898,240 B
#define OFF_NP   OFF_OFF                         // 16*32*10*64*4 = 1,310,720 B (aliases off_t, dead by then)
#define OFF_DP   (OFF_OFF + 1310720ll)           // 16*32*16*4    =    32,768 B
#define OFF_SBN  (59908096ll)   // f32 64
#define OFF_TBN  (59908352ll)   // f32 64
#define OFF_W1   (59908608ll)   // bf16 9*32*64*8 = 147456   =    294,912 B
#define OFF_W2   (60203520ll)   // bf16 9*8*32*8  = 18432    =     36,864 B
#define OFF_W3   (60240384ll)   // bf16 9*8*64*8  = 36864    =     73,728 B
#define WS_NEEDED (60314112ll)

// ---------------- prep: weight repack (frag-order, bf16) + BN fold ----------------
__global__ void k_prep(const float* __restrict__ conv1_w, const float* __restrict__ conv1_b,
                       const float* __restrict__ bn_gamma, const float* __restrict__ bn_beta,
                       const float* __restrict__ bn_mean, const float* __restrict__ bn_var,
                       const float* __restrict__ off_w, const float* __restrict__ mod_w,
                       const float* __restrict__ dcn_w,
                       unsigned short* __restrict__ w1, unsigned short* __restrict__ w2,
                       unsigned short* __restrict__ w3,
                       float* __restrict__ sbn, float* __restrict__ tbn)
{
  int e = blockIdx.x * 256 + threadIdx.x;
  if (e < 147456) {
    int j = e & 7, o = (e >> 3) & 63, cg = (e >> 9) & 31, t = e >> 14;
    w1[e] = f2b(conv1_w[(o * 256 + cg * 8 + j) * 9 + t]);
  } else if (e < 147456 + 18432) {
    int i = e - 147456;
    int j = i & 7, o = (i >> 3) & 31, cg = (i >> 8) & 7, t = i >> 11;
    int ch = cg * 8 + j;
    float v = 0.f;
    if (o < 18)      v = off_w[(o * 64 + ch) * 9 + t];
    else if (o < 27) v = mod_w[((o - 18) * 64 + ch) * 9 + t];
    w2[i] = f2b(v);
  } else if (e < 147456 + 18432 + 36864) {
    int i = e - 147456 - 18432;
    int j = i & 7, o = (i >> 3) & 63, cg = (i >> 9) & 7, t = i >> 12;
    w3[i] = f2b(dcn_w[(o * 64 + cg * 8 + j) * 9 + t]);
  } else {
    int i = e - (147456 + 18432 + 36864);
    if (i < 64) {
      sbn[i] = bn_gamma[i] * rsqrtf(bn_var[i] + 1e-5f);
    } else if (i < 128) {
      int q = i - 64;
      float s = bn_gamma[q] * rsqrtf(bn_var[q] + 1e-5f);
      tbn[q] = (conv1_b[q] - bn_mean[q]) * s + bn_beta[q];
    }
  }
}

// ---------------- conv1 (256->64) + BN + ReLU, MFMA bf16, NHWC output ----------------
__global__ __launch_bounds__(256)
void k_conv1(const float* __restrict__ x, const unsigned short* __restrict__ w1,
             const float* __restrict__ sbn, const float* __restrict__ tbn,
             unsigned short* __restrict__ y1)
{
  __shared__ __align__(16) unsigned short xs[4][98][48];   // [r][wp][c]
  __shared__ __align__(16) unsigned short As[9 * 4 * 64 * 8];

  const int tid = threadIdx.x;
  const int lane = tid & 63, wv = tid >> 6;
  const int l16 = lane & 15, lg = lane >> 4;
  const int wrow = wv & 1, wch = wv >> 1;
  const int h0 = blockIdx.x * 2;
  const int n = blockIdx.y;
  const float* xn = x + (size_t)n * CIN * HW;

  f32x4 acc[2][6];
  #pragma unroll
  for (int a = 0; a < 2; ++a)
    #pragma unroll
    for (int b = 0; b < 6; ++b) { f32x4 z = {0.f,0.f,0.f,0.f}; acc[a][b] = z; }

  for (int chunk = 0; chunk < 8; ++chunk) {
    const int c0 = chunk * 32;
    __syncthreads();
    #pragma unroll
    for (int it = 0; it < 12; ++it) {
      int idx = tid + it * 256;              // < 3072
      int c = idx & 31;
      int w4 = (idx >> 5) % 24;
      int r = idx / 768;
      int row = h0 - 1 + r;
      f32x4 v = {0.f,0.f,0.f,0.f};
      if (row >= 0 && row < HH)
        v = *reinterpret_cast<const f32x4*>(xn + (c0 + c) * HW + row * WW + w4 * 4);
      int wp = w4 * 4 + 1;
      xs[r][wp + 0][c] = f2b(v[0]);
      xs[r][wp + 1][c] = f2b(v[1]);
      xs[r][wp + 2][c] = f2b(v[2]);
      xs[r][wp + 3][c] = f2b(v[3]);
      if (w4 == 0)  xs[r][0][c]  = 0;
      if (w4 == 23) xs[r][97][c] = 0;
    }
    #pragma unroll
    for (int it = 0; it < 9; ++it) {
      int idx = tid + it * 256;              // < 2304
      int o = idx & 63, g = (idx >> 6) & 3, t = idx >> 8;
      *reinterpret_cast<u32x4*>(&As[((t * 4 + g) * 64 + o) * 8]) =
        *reinterpret_cast<const u32x4*>(&w1[((t * 32 + chunk * 4 + g) * 64 + o) * 8]);
    }
    __syncthreads();
    #pragma unroll
    for (int t = 0; t < 9; ++t) {
      const int ky = t / 3, kx = t % 3;
      bf16x8 a0 = *reinterpret_cast<const bf16x8*>(&As[((t*4 + lg)*64 + wch*32 + l16)*8]);
      bf16x8 a1 = *reinterpret_cast<const bf16x8*>(&As[((t*4 + lg)*64 + wch*32 + 16 + l16)*8]);
      const int r = wrow + ky;
      #pragma unroll
      for (int wt = 0; wt < 6; ++wt) {
        bf16x8 b = *reinterpret_cast<const bf16x8*>(&xs[r][wt*16 + l16 + kx][lg*8]);
        acc[0][wt] = MFMA16(a0, b, acc[0][wt]);
        acc[1][wt] = MFMA16(a1, b, acc[1][wt]);
      }
    }
  }
  // epilogue: BN + ReLU -> LDS transpose -> coalesced NHWC store
  __syncthreads();
  unsigned short* ys = &xs[0][0][0];          // reuse as [2][96][72]
  #pragma unroll
  for (int ct = 0; ct < 2; ++ct) {
    #pragma unroll
    for (int j = 0; j < 4; ++j) {
      int o = wch * 32 + ct * 16 + lg * 4 + j;
      float s = sbn[o], tt = tbn[o];
      #pragma unroll
      for (int wt = 0; wt < 6; ++wt) {
        float v = acc[ct][wt][j] * s + tt;
        v = v > 0.f ? v : 0.f;
        ys[((wrow * 96 + wt * 16 + l16) * 72) + o] = f2b(v);
      }
    }
  }
  __syncthreads();
  #pragma unroll
  for (int it = 0; it < 6; ++it) {
    int idx = tid + it * 256;                 // 1536 = 2r * 96p * 8cg
    int cg = idx & 7, p = (idx >> 3) % 96, r = idx / 768;
    *reinterpret_cast<u32x4*>(&y1[(((size_t)(n * HH + h0 + r)) * WW + p) * 64 + cg * 8]) =
      *reinterpret_cast<const u32x4*>(&ys[(r * 96 + p) * 72 + cg * 8]);
  }
}

// ---------------- off/mod conv (64 -> 18+9), MFMA bf16, NHWC input, A in regs ----------------
__global__ __launch_bounds__(256)
void k_conv2(const unsigned short* __restrict__ y1, const unsigned short* __restrict__ w2,
             const float* __restrict__ off_b, const float* __restrict__ mod_b,
             float* __restrict__ off_o, float* __restrict__ mod_o)
{
  __shared__ __align__(16) unsigned short xs[4][98][48];

  const int tid = threadIdx.x;
  const int lane = tid & 63, wv = tid >> 6;
  const int l16 = lane & 15, lg = lane >> 4;
  const int wrow = wv & 1, wct = wv >> 1;
  const int h0 = blockIdx.x * 2;
  const int n = blockIdx.y;
  const unsigned short* y1n = y1 + (size_t)n * HW * CD;

  bf16x8 aR[2][9];
  #pragma unroll
  for (int ch = 0; ch < 2; ++ch)
    #pragma unroll
    for (int t = 0; t < 9; ++t)
      aR[ch][t] = *reinterpret_cast<const bf16x8*>(
          &w2[((t * 8 + ch * 4 + lg) * 32 + wct * 16 + l16) * 8]);

  f32x4 acc[6];
  #pragma unroll
  for (int b = 0; b < 6; ++b) { f32x4 z = {0.f,0.f,0.f,0.f}; acc[b] = z; }

  #pragma unroll
  for (int chunk = 0; chunk < 2; ++chunk) {
    const int c0 = chunk * 32;
    __syncthreads();
    #pragma unroll
    for (int it = 0; it < 6; ++it) {
      int idx = tid + it * 256;             // 1536 = 4r x 96w x 4cg
      int cg = idx & 3, w = (idx >> 2) % 96, r = idx / 384;
      int row = h0 - 1 + r;
      u32x4 v = {0u,0u,0u,0u};
      if (row >= 0 && row < HH)
        v = *reinterpret_cast<const u32x4*>(&y1n[((size_t)row * WW + w) * 64 + c0 + cg * 8]);
      *reinterpret_cast<u32x4*>(&xs[r][w + 1][cg * 8]) = v;
    }
    if (tid < 32) {
      int r = tid >> 3, side = (tid >> 2) & 1, cg = tid & 3;
      u32x4 z = {0u,0u,0u,0u};
      *reinterpret_cast<u32x4*>(&xs[r][side * 97][cg * 8]) = z;
    }
    __syncthreads();
    #pragma unroll
    for (int t = 0; t < 9; ++t) {
      const int ky = t / 3, kx = t % 3;
      const int r = wrow + ky;
      #pragma unroll
      for (int wt = 0; wt < 6; ++wt) {
        bf16x8 b = *reinterpret_cast<const bf16x8*>(&xs[r][wt*16 + l16 + kx][lg*8]);
        acc[wt] = MFMA16(aR[chunk][t], b, acc[wt]);
      }
    }
  }
  const int h = h0 + wrow;
  #pragma unroll
  for (int j = 0; j < 4; ++j) {
    int o = wct * 16 + lg * 4 + j;
    if (o < 18) {
      float bo = off_b[o];
      #pragma unroll
      for (int wt = 0; wt < 6; ++wt)
        off_o[((n * 18 + o) * HH + h) * WW + wt * 16 + l16] = acc[wt][j] + bo;
    } else if (o < 27) {
      int q = o - 18;
      float bo = mod_b[q];
      #pragma unroll
      for (int wt = 0; wt < 6; ++wt) {
        float v = acc[wt][j] + bo;
        mod_o[((n * 9 + q) * HH + h) * WW + wt * 16 + l16] = 2.f / (1.f + expf(-v));
      }
    }
  }
}

// ---------------- deformable conv (DCNv2), NHWC gather, MFMA bf16 ----------------
__global__ __launch_bounds__(256)
void k_dcn(const unsigned short* __restrict__ y1, const float* __restrict__ off_i,
           const float* __restrict__ mod_i, const unsigned short* __restrict__ w3,
           const float* __restrict__ dcn_b, unsigned short* __restrict__ y2)
{
  __shared__ __align__(16) f32x4 wgt[864];
  __shared__ __align__(16) i32x4 ofs[864];
  __shared__ __align__(16) unsigned short Bs[96][72];

  const int tid = threadIdx.x;
  const int lane = tid & 63, wv = tid >> 6;
  const int l16 = lane & 15, lg = lane >> 4;
  const int h = blockIdx.x, n = blockIdx.y;

  // preload A fragments (9 taps x 2 K-chunks)
  bf16x8 aW[9][2];
  #pragma unroll
  for (int t = 0; t < 9; ++t)
    #pragma unroll
    for (int kk = 0; kk < 2; ++kk)
      aW[t][kk] = *reinterpret_cast<const bf16x8*>(
          &w3[((t * 8 + kk * 4 + lg) * 64 + wv * 16 + l16) * 8]);

  // tap metadata: bilinear weights (validity-zeroed, x mod) + clamped element offsets
  #pragma unroll
  for (int it = 0; it < 4; ++it) {
    int e = tid + it * 256;
    if (e < 864) {
      int k = e / 96, p = e % 96;
      float dy = off_i[((n * 18 + 2 * k) * HH + h) * WW + p];
      float dx = off_i[((n * 18 + 2 * k + 1) * HH + h) * WW + p];
      float mw = mod_i[((n * 9 + k) * HH + h) * WW + p];
      float py = (float)(h + k / 3 - 1) + dy;
      float px = (float)(p + k % 3 - 1) + dx;
      float y0f = floorf(py), x0f = floorf(px);
      float wy = py - y0f, wx = px - x0f;
      int iy0 = (int)y0f, ix0 = (int)x0f;
      int iy1 = iy0 + 1, ix1 = ix0 + 1;
      float vy0 = (iy0 >= 0 && iy0 < HH) ? 1.f : 0.f;
      float vy1 = (iy1 >= 0 && iy1 < HH) ? 1.f : 0.f;
      float vx0 = (ix0 >= 0 && ix0 < WW) ? 1.f : 0.f;
      float vx1 = (ix1 >= 0 && ix1 < WW) ? 1.f : 0.f;
      f32x4 w4;
      w4[0] = (1.f - wy) * (1.f - wx) * mw * vy0 * vx0;
      w4[1] = (1.f - wy) * wx         * mw * vy0 * vx1;
      w4[2] = wy         * (1.f - wx) * mw * vy1 * vx0;
      w4[3] = wy         * wx         * mw * vy1 * vx1;
      wgt[e] = w4;
      int cy0 = iy0 < 0 ? 0 : (iy0 > 95 ? 95 : iy0);
      int cy1 = iy1 < 0 ? 0 : (iy1 > 95 ? 95 : iy1);
      int cx0 = ix0 < 0 ? 0 : (ix0 > 95 ? 95 : ix0);
      int cx1 = ix1 < 0 ? 0 : (ix1 > 95 ? 95 : ix1);
      i32x4 o4;
      o4[0] = (cy0 * WW + cx0) * 64; o4[1] = (cy0 * WW + cx1) * 64;
      o4[2] = (cy1 * WW + cx0) * 64; o4[3] = (cy1 * WW + cx1) * 64;
      ofs[e] = o4;
    }
  }
  __syncthreads();

  const unsigned short* y1n = y1 + (size_t)n * HW * CD;
  f32x4 acc[6];
  #pragma unroll
  for (int b = 0; b < 6; ++b) { f32x4 z = {0.f,0.f,0.f,0.f}; acc[b] = z; }

  #pragma unroll
  for (int t = 0; t < 9; ++t) {
    // stage B_t: Bs[p][c] = mod * bilinear(y1), vectorized 8-ch per lane
    #pragma unroll
    for (int it = 0; it < 3; ++it) {
      int idx = tid + it * 256;           // 768 = 96p x 8cg
      int cg = idx & 7, p = idx >> 3;
      f32x4 w4 = wgt[t * 96 + p];
      i32x4 o4 = ofs[t * 96 + p];
      ushort8 g0 = *reinterpret_cast<const ushort8*>(&y1n[o4[0] + cg * 8]);
      ushort8 g1 = *reinterpret_cast<const ushort8*>(&y1n[o4[1] + cg * 8]);
      ushort8 g2 = *reinterpret_cast<const ushort8*>(&y1n[o4[2] + cg * 8]);
      ushort8 g3 = *reinterpret_cast<const ushort8*>(&y1n[o4[3] + cg * 8]);
      unsigned int wds[4];
      #pragma unroll
      for (int q = 0; q < 4; ++q) {
        float va = w4[0]*b2f(g0[2*q])   + w4[1]*b2f(g1[2*q])
                 + w4[2]*b2f(g2[2*q])   + w4[3]*b2f(g3[2*q]);
        float vb = w4[0]*b2f(g0[2*q+1]) + w4[1]*b2f(g1[2*q+1])
                 + w4[2]*b2f(g2[2*q+1]) + w4[3]*b2f(g3[2*q+1]);
        wds[q] = (unsigned int)f2b(va) | ((unsigned int)f2b(vb) << 16);
      }
      u32x4 pk = {wds[0], wds[1], wds[2], wds[3]};
      *reinterpret_cast<u32x4*>(&Bs[p][cg * 8]) = pk;
    }
    __syncthreads();
    #pragma unroll
    for (int kk = 0; kk < 2; ++kk) {
      #pragma unroll
      for (int wt = 0; wt < 6; ++wt) {
        bf16x8 b = *reinterpret_cast<const bf16x8*>(&Bs[wt * 16 + l16][kk * 32 + lg * 8]);
        acc[wt] = MFMA16(aW[t][kk], b, acc[wt]);
      }
    }
    __syncthreads();
  }

  // epilogue: bias -> LDS transpose (alias wgt) -> coalesced NCHW store
  unsigned short* Bs2 = reinterpret_cast<unsigned short*>(wgt);   // [64][104]
  #pragma unroll
  for (int j = 0; j < 4; ++j) {
    int o = wv * 16 + lg * 4 + j;
    float bo = dcn_b[o];
    #pragma unroll
    for (int wt = 0; wt < 6; ++wt)
      Bs2[o * 104 + wt * 16 + l16] = f2b(acc[wt][j] + bo);
  }
  __syncthreads();
  #pragma unroll
  for (int it = 0; it < 3; ++it) {
    int idx = tid + it * 256;             // 768 = 64o x 12seg
    int seg = idx % 12, o = idx / 12;
    *reinterpret_cast<u32x4*>(&y2[(((size_t)n * CD + o) * HH + h) * WW + seg * 8]) =
      *reinterpret_cast<const u32x4*>(&Bs2[o * 104 + seg * 8]);
  }
}

// ---------------- mask resize: bilinear x0.5 == 2x2 average ----------------
__global__ void k_resize(const float* __restrict__ masks, float* __restrict__ m)
{
  int gid = blockIdx.x * 256 + threadIdx.x;
  if (gid >= 16 * 10 * HW) return;
  int pix = gid % HW;
  int r = gid / HW;
  int oh = pix / WW, ow = pix % WW;
  const float* s = masks + ((size_t)r * 192 + 2 * oh) * 192 + 2 * ow;
  m[gid] = 0.25f * (s[0] + s[1] + s[192] + s[193]);
}

// ---------------- pooling partials (f32, deterministic) ----------------
// grid (32 seg, 16 bf). per block: 288 pixels, all 10 masks x 64 ch.
__global__ __launch_bounds__(256)
void k_pool(const unsigned short* __restrict__ y2, const float* __restrict__ m,
            float* __restrict__ num_part, float* __restrict__ den_part)
{
  __shared__ float ms[10][288];
  __shared__ float red[4][10][64];
  __shared__ float den_red[10][16];
  const int tid = threadIdx.x;
  const int seg = blockIdx.x, bf = blockIdx.y;
  const int p0 = seg * 288;

  #pragma unroll
  for (int it = 0; it < 12; ++it) {
    int idx = tid + it * 256;              // < 2880
    if (idx < 2880) {
      int i = idx / 288, p = idx % 288;
      ms[i][p] = m[(bf * 10 + i) * HW + p0 + p];
    }
  }
  __syncthreads();

  const int c = tid & 63, grp = tid >> 6;
  float acc[10];
  #pragma unroll
  for (int i = 0; i < 10; ++i) acc[i] = 0.f;
  const unsigned short* yrow = y2 + (size_t)(bf * 64 + c) * HW + p0 + grp * 72;
  for (int qb = 0; qb < 18; ++qb) {
    u16x4 yv = *reinterpret_cast<const u16x4*>(yrow + qb * 4);
    float v0 = b2f(yv[0]), v1 = b2f(yv[1]), v2 = b2f(yv[2]), v3 = b2f(yv[3]);
    int pp = grp * 72 + qb * 4;
    #pragma unroll
    for (int i = 0; i < 10; ++i) {
      f32x4 mv = *reinterpret_cast<const f32x4*>(&ms[i][pp]);
      acc[i] += v0 * mv[0] + v1 * mv[1] + v2 * mv[2] + v3 * mv[3];
    }
  }
  #pragma unroll
  for (int i = 0; i < 10; ++i) red[grp][i][c] = acc[i];
  if (tid < 160) {
    int i = tid >> 4, s16 = tid & 15;
    float s = 0.f;
    for (int k2 = 0; k2 < 18; ++k2) s += ms[i][s16 + k2 * 16];
    den_red[i][s16] = s;
  }
  __syncthreads();
  #pragma unroll
  for (int it = 0; it < 3; ++it) {
    int e = tid + it * 256;
    if (e < 640) {
      int i = e >> 6, cc = e & 63;
      num_part[((bf * 32 + seg) * 10 + i) * 64 + cc] =
        red[0][i][cc] + red[1][i][cc] + red[2][i][cc] + red[3][i][cc];
    }
  }
  if (tid < 10) {
    float s = 0.f;
    for (int k2 = 0; k2 < 16; ++k2) s += den_red[tid][k2];
    den_part[(bf * 32 + seg) * 16 + tid] = s;
  }
}

// ---------------- head ----------------
__global__ void k_head(const float* __restrict__ num_part, const float* __restrict__ den_part,
                       const float* __restrict__ smooth_w, const float* __restrict__ smooth_b,
                       const float* __restrict__ inc_w, const float* __restrict__ pix_w,
                       float* __restrict__ out)
{
  __shared__ float pool_s[10][64];
  __shared__ float feat_s[10][64];
  const int tid = threadIdx.x;
  const int bf = blockIdx.x;
  #pragma unroll
  for (int it = 0; it < 3; ++it) {
    int e = tid + it * 256;
    if (e < 640) {
      int i = e >> 6, cc = e & 63;
      float nsum = 0.f, dsum = 0.f;
      for (int s = 0; s < 32; ++s) {
        nsum += num_part[((bf * 32 + s) * 10 + i) * 64 + cc];
        dsum += den_part[(bf * 32 + s) * 16 + i];
      }
      pool_s[i][cc] = nsum / (dsum + 1e-6f);
    }
  }
  __syncthreads();
  #pragma unroll
  for (int it = 0; it < 3; ++it) {
    int e = tid + it * 256;
    if (e < 640) {
      int i = e >> 6, cc = e & 63;
      float s = smooth_b[cc];
      for (int k = 0; k < 64; ++k) s += pool_s[i][k] * smooth_w[cc * 64 + k];
      feat_s[i][cc] = s > 0.f ? s : 0.f;
    }
  }
  __syncthreads();
  #pragma unroll
  for (int it = 0; it < 5; ++it) {
    int e = tid + it * 256;
    if (e < 1280) {
      int i = e >> 7, oc = e & 127;
      float s = 0.f;
      for (int k = 0; k < 64; ++k) s += feat_s[i][k] * inc_w[oc * 64 + k];
      out[(bf * 10 + i) * 128 + oc] = s;
    }
  }
  #pragma unroll
  for (int it = 0; it < 3; ++it) {
    int e = tid + it * 256;
    if (e < 640) {
      int i = e >> 6, oc = e & 63;
      float s = 0.f;
      for (int k = 0; k < 64; ++k) s += feat_s[i][k] * pix_w[oc * 64 + k];
      out[20480 + (bf * 10 + i) * 64 + oc] = s;
    }
  }
}

// ---------------- launch ----------------
extern "C" void kernel_launch(void* const* d_in, const int* in_sizes, int n_in,
                              void* d_out, int out_size, void* d_ws, size_t ws_size,
                              hipStream_t stream)
{
  const float* x        = (const float*)d_in[0];
  const float* masks    = (const float*)d_in[1];
  const float* conv1_w  = (const float*)d_in[2];
  const float* conv1_b  = (const float*)d_in[3];
  const float* bn_gamma = (const float*)d_in[4];
  const float* bn_beta  = (const float*)d_in[5];
  const float* bn_mean  = (const float*)d_in[6];
  const float* bn_var   = (const float*)d_in[7];
  const float* off_w    = (const float*)d_in[8];
  const float* off_b    = (const float*)d_in[9];
  const float* mod_w    = (const float*)d_in[10];
  const float* mod_b    = (const float*)d_in[11];
  const float* dcn_w    = (const float*)d_in[12];
  const float* dcn_b    = (const float*)d_in[13];
  const float* smooth_w = (const float*)d_in[14];
  const float* smooth_b = (const float*)d_in[15];
  const float* inc_w    = (const float*)d_in[16];
  const float* pix_w    = (const float*)d_in[17];
  float* out = (float*)d_out;

  if (ws_size < (size_t)WS_NEEDED) return;
  char* ws = (char*)d_ws;
  unsigned short* y1  = (unsigned short*)(ws + OFF_Y1);
  unsigned short* y2  = (unsigned short*)(ws + OFF_Y2);
  float* off_t        = (float*)(ws + OFF_OFF);
  float* mod_t        = (float*)(ws + OFF_MOD);
  float* mbuf         = (float*)(ws + OFF_M);
  float* num_part     = (float*)(ws + OFF_NP);
  float* den_part     = (float*)(ws + OFF_DP);
  float* sbn          = (float*)(ws + OFF_SBN);
  float* tbn          = (float*)(ws + OFF_TBN);
  unsigned short* w1  = (unsigned short*)(ws + OFF_W1);
  unsigned short* w2  = (unsigned short*)(ws + OFF_W2);
  unsigned short* w3  = (unsigned short*)(ws + OFF_W3);

  k_prep<<<793, 256, 0, stream>>>(conv1_w, conv1_b, bn_gamma, bn_beta, bn_mean, bn_var,
                                  off_w, mod_w, dcn_w, w1, w2, w3, sbn, tbn);
  k_conv1<<<dim3(48, 16), 256, 0, stream>>>(x, w1, sbn, tbn, y1);
  k_conv2<<<dim3(48, 16), 256, 0, stream>>>(y1, w2, off_b, mod_b, off_t, mod_t);
  k_dcn<<<dim3(96, 16), 256, 0, stream>>>(y1, off_t, mod_t, w3, dcn_b, y2);
  k_resize<<<(16 * 10 * HW + 255) / 256, 256, 0, stream>>>(masks, mbuf);
  k_pool<<<dim3(32, 16), 256, 0, stream>>>(y2, mbuf, num_part, den_part);
  k_head<<<16, 256, 0, stream>>>(num_part, den_part, smooth_w, smooth_b, inc_w, pix_w, out);
}

// Round 3
// 486.297 us; speedup vs baseline: 1.2734x; 1.0486x over previous
//
#include <hip/hip_runtime.h>
#include <hip/hip_bf16.h>

// ---------------- types / helpers ----------------
typedef __attribute__((ext_vector_type(8))) __bf16 bf16x8;
typedef __attribute__((ext_vector_type(4))) float f32x4;
typedef __attribute__((ext_vector_type(4))) unsigned int u32x4;
typedef __attribute__((ext_vector_type(2))) unsigned int u32x2;
typedef __attribute__((ext_vector_type(4))) unsigned short u16x4;
typedef __attribute__((ext_vector_type(8))) unsigned short ushort8;

#define MFMA16(a,b,c) __builtin_amdgcn_mfma_f32_16x16x32_bf16((a),(b),(c),0,0,0)

__device__ __forceinline__ float b2f(unsigned short u) {
  union { unsigned int i; float f; } v; v.i = ((unsigned int)u) << 16; return v.f;
}
__device__ __forceinline__ unsigned short f2b(float f) {
  union { float f; unsigned int u; } v; v.f = f;
  unsigned int u = v.u;
  unsigned int r = (u + 0x7fffu + ((u >> 16) & 1u)) >> 16;  // RTNE
  return (unsigned short)r;
}
__device__ __forceinline__ unsigned short f2h(float f) {
  _Float16 x = (_Float16)f; unsigned short r; __builtin_memcpy(&r, &x, 2); return r;
}
__device__ __forceinline__ float h2f(unsigned short h) {
  _Float16 x; __builtin_memcpy(&x, &h, 2); return (float)x;
}

#define NIMG 16
#define CIN  256
#define CD   64
#define HH   96
#define WW   96
#define HW   (HH*WW)          // 9216

// ---------------- workspace byte offsets ----------------
#define OFF_Y1   (0ll)          // bf16 NHWC 16*9216*64      = 18,874,368 B
#define OFF_Y2   (18874368ll)   // bf16 NHWC same size; ALSO xT (8img NHWC bf16 = 37,748,736 B) during conv1 phase
#define OFF_OFF  (37748736ll)   // f32  16*18*9216           = 10,616,832 B
#define OFF_MOD  (48365568ll)   // f32  16*9*9216            =  5,308,416 B
#define OFF_M    (53673984ll)   // f32  16*10*9216           =  5,898,240 B
#define OFF_NP   OFF_OFF                         // 16*32*10*64*4 = 1,310,720 B (aliases off_t, dead by then)
#define OFF_DP   (OFF_OFF + 1310720ll)           // 16*32*16*4    =    32,768 B
#define OFF_SBN  (59908096ll)   // f32 64
#define OFF_TBN  (59908352ll)   // f32 64
#define OFF_W1   (59908608ll)   // bf16 9*32*64*8 = 147456   =    294,912 B
#define OFF_W2   (60203520ll)   // bf16 9*8*32*8  = 18432    =     36,864 B
#define OFF_W3   (60240384ll)   // bf16 9*8*64*8  = 36864    =     73,728 B
#define WS_NEEDED (60314112ll)

// ---------------- prep: weight repack (frag-order, bf16) + BN fold ----------------
__global__ void k_prep(const float* __restrict__ conv1_w, const float* __restrict__ conv1_b,
                       const float* __restrict__ bn_gamma, const float* __restrict__ bn_beta,
                       const float* __restrict__ bn_mean, const float* __restrict__ bn_var,
                       const float* __restrict__ off_w, const float* __restrict__ mod_w,
                       const float* __restrict__ dcn_w,
                       unsigned short* __restrict__ w1, unsigned short* __restrict__ w2,
                       unsigned short* __restrict__ w3,
                       float* __restrict__ sbn, float* __restrict__ tbn)
{
  int e = blockIdx.x * 256 + threadIdx.x;
  if (e < 147456) {
    int j = e & 7, o = (e >> 3) & 63, cg = (e >> 9) & 31, t = e >> 14;
    w1[e] = f2b(conv1_w[(o * 256 + cg * 8 + j) * 9 + t]);
  } else if (e < 147456 + 18432) {
    int i = e - 147456;
    int j = i & 7, o = (i >> 3) & 31, cg = (i >> 8) & 7, t = i >> 11;
    int ch = cg * 8 + j;
    float v = 0.f;
    if (o < 18)      v = off_w[(o * 64 + ch) * 9 + t];
    else if (o < 27) v = mod_w[((o - 18) * 64 + ch) * 9 + t];
    w2[i] = f2b(v);
  } else if (e < 147456 + 18432 + 36864) {
    int i = e - 147456 - 18432;
    int j = i & 7, o = (i >> 3) & 63, cg = (i >> 9) & 7, t = i >> 12;
    w3[i] = f2b(dcn_w[(o * 64 + cg * 8 + j) * 9 + t]);
  } else {
    int i = e - (147456 + 18432 + 36864);
    if (i < 64) {
      sbn[i] = bn_gamma[i] * rsqrtf(bn_var[i] + 1e-5f);
    } else if (i < 128) {
      int q = i - 64;
      float s = bn_gamma[q] * rsqrtf(bn_var[q] + 1e-5f);
      tbn[q] = (conv1_b[q] - bn_mean[q]) * s + bn_beta[q];
    }
  }
}

// ---------------- transpose x NCHW f32 -> NHWC bf16, 8 images per pass ----------------
// grid (144 ptile, 4 ctile, 8 img). tile 64p x 64c.
__global__ __launch_bounds__(256)
void k_tr(const float* __restrict__ x, unsigned short* __restrict__ xT, int n_base)
{
  __shared__ __align__(16) unsigned short ls[64][68];
  const int tid = threadIdx.x;
  const int p0 = blockIdx.x * 64, c0 = blockIdx.y * 64, nl = blockIdx.z;
  const float* xn = x + (size_t)(n_base + nl) * CIN * HW;

  const int p4 = tid & 15, cb = tid >> 4;
  #pragma unroll
  for (int it = 0; it < 4; ++it) {
    int c = cb + it * 16;
    f32x4 v = *reinterpret_cast<const f32x4*>(xn + (size_t)(c0 + c) * HW + p0 + p4 * 4);
    #pragma unroll
    for (int q = 0; q < 4; ++q) ls[p4 * 4 + q][c] = f2b(v[q]);
  }
  __syncthreads();
  const int cg = tid & 7, pb = tid >> 3;
  #pragma unroll
  for (int it = 0; it < 2; ++it) {
    int p = pb + it * 32;
    u32x2 lo = *reinterpret_cast<const u32x2*>(&ls[p][cg * 8]);
    u32x2 hi = *reinterpret_cast<const u32x2*>(&ls[p][cg * 8 + 4]);
    u32x4 v = {lo[0], lo[1], hi[0], hi[1]};
    *reinterpret_cast<u32x4*>(&xT[((size_t)nl * HW + p0 + p) * CIN + c0 + cg * 8]) = v;
  }
}

// ---------------- conv1 (256->64) + BN + ReLU, NHWC in/out, MFMA bf16 ----------------
// grid (48, 8 local img). A-frags from global (L2). 2 output rows per block.
__global__ __launch_bounds__(256)
void k_conv1t(const unsigned short* __restrict__ xT, const unsigned short* __restrict__ w1,
              const float* __restrict__ sbn, const float* __restrict__ tbn,
              unsigned short* __restrict__ y1, int n_base)
{
  __shared__ __align__(16) unsigned short xs[4][98][40];   // 31,360 B

  const int tid = threadIdx.x;
  const int lane = tid & 63, wv = tid >> 6;
  const int l16 = lane & 15, lg = lane >> 4;
  const int wrow = wv & 1, wch = wv >> 1;
  const int h0 = blockIdx.x * 2;
  const int nl = blockIdx.y;
  const int n = n_base + nl;
  const unsigned short* xn = xT + (size_t)nl * HW * CIN;

  f32x4 acc[2][6];
  #pragma unroll
  for (int a = 0; a < 2; ++a)
    #pragma unroll
    for (int b = 0; b < 6; ++b) { f32x4 z = {0.f,0.f,0.f,0.f}; acc[a][b] = z; }

  for (int chunk = 0; chunk < 8; ++chunk) {
    const int c0 = chunk * 32;
    __syncthreads();
    // stage: 4r x 96w x 32c, direct NHWC copy (coalesced 16B)
    #pragma unroll
    for (int it = 0; it < 6; ++it) {
      int idx = tid + it * 256;             // 1536 = 4r x 96w x 4cg
      int cg = idx & 3, w = (idx >> 2) % 96, r = idx / 384;
      int row = h0 - 1 + r;
      u32x4 v = {0u,0u,0u,0u};
      if (row >= 0 && row < HH)
        v = *reinterpret_cast<const u32x4*>(&xn[((size_t)row * WW + w) * CIN + c0 + cg * 8]);
      *reinterpret_cast<u32x4*>(&xs[r][w + 1][cg * 8]) = v;
    }
    if (tid < 32) {
      int r = tid >> 3, side = (tid >> 2) & 1, cg = tid & 3;
      u32x4 z = {0u,0u,0u,0u};
      *reinterpret_cast<u32x4*>(&xs[r][side * 97][cg * 8]) = z;
    }
    __syncthreads();
    #pragma unroll
    for (int t = 0; t < 9; ++t) {
      const int ky = t / 3, kx = t % 3;
      bf16x8 a0 = *reinterpret_cast<const bf16x8*>(
          &w1[((t * 32 + chunk * 4 + lg) * 64 + wch * 32 + l16) * 8]);
      bf16x8 a1 = *reinterpret_cast<const bf16x8*>(
          &w1[((t * 32 + chunk * 4 + lg) * 64 + wch * 32 + 16 + l16) * 8]);
      const int r = wrow + ky;
      #pragma unroll
      for (int wt = 0; wt < 6; ++wt) {
        bf16x8 b = *reinterpret_cast<const bf16x8*>(&xs[r][wt*16 + l16 + kx][lg*8]);
        acc[0][wt] = MFMA16(a0, b, acc[0][wt]);
        acc[1][wt] = MFMA16(a1, b, acc[1][wt]);
      }
    }
  }
  // epilogue: BN + ReLU -> LDS transpose -> coalesced NHWC store
  __syncthreads();
  unsigned short* ys = &xs[0][0][0];          // reuse as [2][96][72]
  #pragma unroll
  for (int ct = 0; ct < 2; ++ct) {
    int o4 = wch * 32 + ct * 16 + lg * 4;
    f32x4 s4 = *reinterpret_cast<const f32x4*>(&sbn[o4]);
    f32x4 t4 = *reinterpret_cast<const f32x4*>(&tbn[o4]);
    #pragma unroll
    for (int wt = 0; wt < 6; ++wt) {
      int p = wrow * 96 + wt * 16 + l16;
      float v0 = acc[ct][wt][0] * s4[0] + t4[0]; v0 = v0 > 0.f ? v0 : 0.f;
      float v1 = acc[ct][wt][1] * s4[1] + t4[1]; v1 = v1 > 0.f ? v1 : 0.f;
      float v2 = acc[ct][wt][2] * s4[2] + t4[2]; v2 = v2 > 0.f ? v2 : 0.f;
      float v3 = acc[ct][wt][3] * s4[3] + t4[3]; v3 = v3 > 0.f ? v3 : 0.f;
      u32x2 d = {(unsigned)f2b(v0) | ((unsigned)f2b(v1) << 16),
                 (unsigned)f2b(v2) | ((unsigned)f2b(v3) << 16)};
      *reinterpret_cast<u32x2*>(&ys[p * 72 + o4]) = d;
    }
  }
  __syncthreads();
  #pragma unroll
  for (int it = 0; it < 6; ++it) {
    int idx = tid + it * 256;                 // 1536 = 2r * 96p * 8cg
    int cg = idx & 7, p = (idx >> 3) % 96, r = idx / 768;
    *reinterpret_cast<u32x4*>(&y1[(((size_t)n * HH + h0 + r) * WW + p) * CD + cg * 8]) =
      *reinterpret_cast<const u32x4*>(&ys[(r * 96 + p) * 72 + cg * 8]);
  }
}

// ---------------- off/mod conv (64 -> 18+9), MFMA bf16, NHWC input ----------------
__global__ __launch_bounds__(256)
void k_conv2(const unsigned short* __restrict__ y1, const unsigned short* __restrict__ w2,
             const float* __restrict__ off_b, const float* __restrict__ mod_b,
             float* __restrict__ off_o, float* __restrict__ mod_o)
{
  __shared__ __align__(16) unsigned short xs[4][98][40];

  const int tid = threadIdx.x;
  const int lane = tid & 63, wv = tid >> 6;
  const int l16 = lane & 15, lg = lane >> 4;
  const int wrow = wv & 1, wct = wv >> 1;
  const int h0 = blockIdx.x * 2;
  const int n = blockIdx.y;
  const unsigned short* y1n = y1 + (size_t)n * HW * CD;

  f32x4 acc[6];
  #pragma unroll
  for (int b = 0; b < 6; ++b) { f32x4 z = {0.f,0.f,0.f,0.f}; acc[b] = z; }

  #pragma unroll
  for (int chunk = 0; chunk < 2; ++chunk) {
    const int c0 = chunk * 32;
    bf16x8 aR[9];
    #pragma unroll
    for (int t = 0; t < 9; ++t)
      aR[t] = *reinterpret_cast<const bf16x8*>(
          &w2[((t * 8 + chunk * 4 + lg) * 32 + wct * 16 + l16) * 8]);
    __syncthreads();
    #pragma unroll
    for (int it = 0; it < 6; ++it) {
      int idx = tid + it * 256;             // 1536 = 4r x 96w x 4cg
      int cg = idx & 3, w = (idx >> 2) % 96, r = idx / 384;
      int row = h0 - 1 + r;
      u32x4 v = {0u,0u,0u,0u};
      if (row >= 0 && row < HH)
        v = *reinterpret_cast<const u32x4*>(&y1n[((size_t)row * WW + w) * CD + c0 + cg * 8]);
      *reinterpret_cast<u32x4*>(&xs[r][w + 1][cg * 8]) = v;
    }
    if (tid < 32) {
      int r = tid >> 3, side = (tid >> 2) & 1, cg = tid & 3;
      u32x4 z = {0u,0u,0u,0u};
      *reinterpret_cast<u32x4*>(&xs[r][side * 97][cg * 8]) = z;
    }
    __syncthreads();
    #pragma unroll
    for (int t = 0; t < 9; ++t) {
      const int ky = t / 3, kx = t % 3;
      const int r = wrow + ky;
      #pragma unroll
      for (int wt = 0; wt < 6; ++wt) {
        bf16x8 b = *reinterpret_cast<const bf16x8*>(&xs[r][wt*16 + l16 + kx][lg*8]);
        acc[wt] = MFMA16(aR[t], b, acc[wt]);
      }
    }
  }
  const int h = h0 + wrow;
  #pragma unroll
  for (int j = 0; j < 4; ++j) {
    int o = wct * 16 + lg * 4 + j;
    if (o < 18) {
      float bo = off_b[o];
      #pragma unroll
      for (int wt = 0; wt < 6; ++wt)
        off_o[((n * 18 + o) * HH + h) * WW + wt * 16 + l16] = acc[wt][j] + bo;
    } else if (o < 27) {
      int q = o - 18;
      float bo = mod_b[q];
      #pragma unroll
      for (int wt = 0; wt < 6; ++wt) {
        float v = acc[wt][j] + bo;
        mod_o[((n * 9 + q) * HH + h) * WW + wt * 16 + l16] = 2.f / (1.f + expf(-v));
      }
    }
  }
}

// ---------------- deformable conv (DCNv2), NHWC gather, NHWC output ----------------
__global__ __launch_bounds__(256)
void k_dcn(const unsigned short* __restrict__ y1, const float* __restrict__ off_i,
           const float* __restrict__ mod_i, const unsigned short* __restrict__ w3g,
           const float* __restrict__ dcn_b, unsigned short* __restrict__ y2)
{
  __shared__ __align__(16) unsigned short meta[864][8];   // 4xf16 weights + 4xu16 pixel idx
  __shared__ __align__(16) unsigned short Bs[96][72];

  const int tid = threadIdx.x;
  const int lane = tid & 63, wv = tid >> 6;
  const int l16 = lane & 15, lg = lane >> 4;
  const int h = blockIdx.x, n = blockIdx.y;

  // tap metadata
  #pragma unroll
  for (int it = 0; it < 4; ++it) {
    int e = tid + it * 256;
    if (e < 864) {
      int k = e / 96, p = e % 96;
      float dy = off_i[((n * 18 + 2 * k) * HH + h) * WW + p];
      float dx = off_i[((n * 18 + 2 * k + 1) * HH + h) * WW + p];
      float mw = mod_i[((n * 9 + k) * HH + h) * WW + p];
      float py = (float)(h + k / 3 - 1) + dy;
      float px = (float)(p + k % 3 - 1) + dx;
      float y0f = floorf(py), x0f = floorf(px);
      float wy = py - y0f, wx = px - x0f;
      int iy0 = (int)y0f, ix0 = (int)x0f;
      int iy1 = iy0 + 1, ix1 = ix0 + 1;
      float vy0 = (iy0 >= 0 && iy0 < HH) ? 1.f : 0.f;
      float vy1 = (iy1 >= 0 && iy1 < HH) ? 1.f : 0.f;
      float vx0 = (ix0 >= 0 && ix0 < WW) ? 1.f : 0.f;
      float vx1 = (ix1 >= 0 && ix1 < WW) ? 1.f : 0.f;
      unsigned short m0 = f2h((1.f - wy) * (1.f - wx) * mw * vy0 * vx0);
      unsigned short m1 = f2h((1.f - wy) * wx         * mw * vy0 * vx1);
      unsigned short m2 = f2h(wy         * (1.f - wx) * mw * vy1 * vx0);
      unsigned short m3 = f2h(wy         * wx         * mw * vy1 * vx1);
      int cy0 = iy0 < 0 ? 0 : (iy0 > 95 ? 95 : iy0);
      int cy1 = iy1 < 0 ? 0 : (iy1 > 95 ? 95 : iy1);
      int cx0 = ix0 < 0 ? 0 : (ix0 > 95 ? 95 : ix0);
      int cx1 = ix1 < 0 ? 0 : (ix1 > 95 ? 95 : ix1);
      u32x4 pk = {(unsigned)m0 | ((unsigned)m1 << 16),
                  (unsigned)m2 | ((unsigned)m3 << 16),
                  (unsigned)(cy0 * WW + cx0) | ((unsigned)(cy0 * WW + cx1) << 16),
                  (unsigned)(cy1 * WW + cx0) | ((unsigned)(cy1 * WW + cx1) << 16)};
      *reinterpret_cast<u32x4*>(&meta[e][0]) = pk;
    }
  }
  __syncthreads();

  const unsigned short* y1n = y1 + (size_t)n * HW * CD;
  f32x4 acc[6];
  #pragma unroll
  for (int b = 0; b < 6; ++b) { f32x4 z = {0.f,0.f,0.f,0.f}; acc[b] = z; }

  #pragma unroll
  for (int t = 0; t < 9; ++t) {
    bf16x8 a0 = *reinterpret_cast<const bf16x8*>(
        &w3g[((t * 8 + lg) * 64 + wv * 16 + l16) * 8]);
    bf16x8 a1 = *reinterpret_cast<const bf16x8*>(
        &w3g[((t * 8 + 4 + lg) * 64 + wv * 16 + l16) * 8]);
    // stage B_t
    #pragma unroll
    for (int it = 0; it < 3; ++it) {
      int idx = tid + it * 256;           // 768 = 96p x 8cg
      int cg = idx & 7, p = idx >> 3;
      u32x4 mk = *reinterpret_cast<const u32x4*>(&meta[t * 96 + p][0]);
      float hw0 = h2f((unsigned short)(mk[0] & 0xffffu));
      float hw1 = h2f((unsigned short)(mk[0] >> 16));
      float hw2 = h2f((unsigned short)(mk[1] & 0xffffu));
      float hw3 = h2f((unsigned short)(mk[1] >> 16));
      int o0 = (int)(mk[2] & 0xffffu) << 6;
      int o1 = (int)(mk[2] >> 16) << 6;
      int o2 = (int)(mk[3] & 0xffffu) << 6;
      int o3 = (int)(mk[3] >> 16) << 6;
      ushort8 g0 = *reinterpret_cast<const ushort8*>(&y1n[o0 + cg * 8]);
      ushort8 g1 = *reinterpret_cast<const ushort8*>(&y1n[o1 + cg * 8]);
      ushort8 g2 = *reinterpret_cast<const ushort8*>(&y1n[o2 + cg * 8]);
      ushort8 g3 = *reinterpret_cast<const ushort8*>(&y1n[o3 + cg * 8]);
      unsigned int wds[4];
      #pragma unroll
      for (int q = 0; q < 4; ++q) {
        float va = hw0*b2f(g0[2*q])   + hw1*b2f(g1[2*q])
                 + hw2*b2f(g2[2*q])   + hw3*b2f(g3[2*q]);
        float vb = hw0*b2f(g0[2*q+1]) + hw1*b2f(g1[2*q+1])
                 + hw2*b2f(g2[2*q+1]) + hw3*b2f(g3[2*q+1]);
        wds[q] = (unsigned int)f2b(va) | ((unsigned int)f2b(vb) << 16);
      }
      u32x4 pk = {wds[0], wds[1], wds[2], wds[3]};
      *reinterpret_cast<u32x4*>(&Bs[p][cg * 8]) = pk;
    }
    __syncthreads();
    #pragma unroll
    for (int wt = 0; wt < 6; ++wt) {
      bf16x8 b0 = *reinterpret_cast<const bf16x8*>(&Bs[wt * 16 + l16][lg * 8]);
      bf16x8 b1 = *reinterpret_cast<const bf16x8*>(&Bs[wt * 16 + l16][32 + lg * 8]);
      acc[wt] = MFMA16(a0, b0, acc[wt]);
      acc[wt] = MFMA16(a1, b1, acc[wt]);
    }
    __syncthreads();
  }

  // epilogue: bias -> LDS transpose (reuse Bs) -> coalesced NHWC store
  unsigned short* Bs2 = &Bs[0][0];
  {
    int o4 = wv * 16 + lg * 4;
    f32x4 b4 = *reinterpret_cast<const f32x4*>(&dcn_b[o4]);
    #pragma unroll
    for (int wt = 0; wt < 6; ++wt) {
      int p = wt * 16 + l16;
      u32x2 d = {(unsigned)f2b(acc[wt][0] + b4[0]) | ((unsigned)f2b(acc[wt][1] + b4[1]) << 16),
                 (unsigned)f2b(acc[wt][2] + b4[2]) | ((unsigned)f2b(acc[wt][3] + b4[3]) << 16)};
      *reinterpret_cast<u32x2*>(&Bs2[p * 72 + o4]) = d;
    }
  }
  __syncthreads();
  #pragma unroll
  for (int it = 0; it < 3; ++it) {
    int idx = tid + it * 256;             // 768 = 96p x 8cg
    int cg = idx & 7, p = idx >> 3;
    *reinterpret_cast<u32x4*>(&y2[(((size_t)n * HH + h) * WW + p) * CD + cg * 8]) =
      *reinterpret_cast<const u32x4*>(&Bs2[p * 72 + cg * 8]);
  }
}

// ---------------- mask resize: bilinear x0.5 == 2x2 average ----------------
__global__ void k_resize(const float* __restrict__ masks, float* __restrict__ m)
{
  int gid = blockIdx.x * 256 + threadIdx.x;
  if (gid >= 16 * 10 * HW) return;
  int pix = gid % HW;
  int r = gid / HW;
  int oh = pix / WW, ow = pix % WW;
  const float* s = masks + ((size_t)r * 192 + 2 * oh) * 192 + 2 * ow;
  m[gid] = 0.25f * (s[0] + s[1] + s[192] + s[193]);
}

// ---------------- pooling partials (f32, deterministic), NHWC y2 ----------------
// grid (32 seg, 16 bf). per block: 288 pixels, all 10 masks x 64 ch.
__global__ __launch_bounds__(256)
void k_pool(const unsigned short* __restrict__ y2, const float* __restrict__ m,
            float* __restrict__ num_part, float* __restrict__ den_part)
{
  __shared__ float ms[10][288];
  __shared__ float red[4][10][64];
  __shared__ float den_red[10][16];
  const int tid = threadIdx.x;
  const int seg = blockIdx.x, bf = blockIdx.y;
  const int p0 = seg * 288;

  #pragma unroll
  for (int it = 0; it < 12; ++it) {
    int idx = tid + it * 256;
    if (idx < 2880) {
      int i = idx / 288, p = idx % 288;
      ms[i][p] = m[(bf * 10 + i) * HW + p0 + p];
    }
  }
  __syncthreads();

  const int c = tid & 63, grp = tid >> 6;
  float acc[10];
  #pragma unroll
  for (int i = 0; i < 10; ++i) acc[i] = 0.f;
  const unsigned short* yb = y2 + ((size_t)bf * HW + p0 + grp * 72) * CD + c;
  for (int p = 0; p < 72; ++p) {
    float v = b2f(yb[p * CD]);
    #pragma unroll
    for (int i = 0; i < 10; ++i) acc[i] += v * ms[i][grp * 72 + p];
  }
  #pragma unroll
  for (int i = 0; i < 10; ++i) red[grp][i][c] = acc[i];
  if (tid < 160) {
    int i = tid >> 4, s16 = tid & 15;
    float s = 0.f;
    for (int k2 = 0; k2 < 18; ++k2) s += ms[i][s16 + k2 * 16];
    den_red[i][s16] = s;
  }
  __syncthreads();
  #pragma unroll
  for (int it = 0; it < 3; ++it) {
    int e = tid + it * 256;
    if (e < 640) {
      int i = e >> 6, cc = e & 63;
      num_part[((bf * 32 + seg) * 10 + i) * 64 + cc] =
        red[0][i][cc] + red[1][i][cc] + red[2][i][cc] + red[3][i][cc];
    }
  }
  if (tid < 10) {
    float s = 0.f;
    for (int k2 = 0; k2 < 16; ++k2) s += den_red[tid][k2];
    den_part[(bf * 32 + seg) * 16 + tid] = s;
  }
}

// ---------------- head ----------------
__global__ void k_head(const float* __restrict__ num_part, const float* __restrict__ den_part,
                       const float* __restrict__ smooth_w, const float* __restrict__ smooth_b,
                       const float* __restrict__ inc_w, const float* __restrict__ pix_w,
                       float* __restrict__ out)
{
  __shared__ float pool_s[10][64];
  __shared__ float feat_s[10][64];
  const int tid = threadIdx.x;
  const int bf = blockIdx.x;
  #pragma unroll
  for (int it = 0; it < 3; ++it) {
    int e = tid + it * 256;
    if (e < 640) {
      int i = e >> 6, cc = e & 63;
      float nsum = 0.f, dsum = 0.f;
      for (int s = 0; s < 32; ++s) {
        nsum += num_part[((bf * 32 + s) * 10 + i) * 64 + cc];
        dsum += den_part[(bf * 32 + s) * 16 + i];
      }
      pool_s[i][cc] = nsum / (dsum + 1e-6f);
    }
  }
  __syncthreads();
  #pragma unroll
  for (int it = 0; it < 3; ++it) {
    int e = tid + it * 256;
    if (e < 640) {
      int i = e >> 6, cc = e & 63;
      float s = smooth_b[cc];
      for (int k = 0; k < 64; ++k) s += pool_s[i][k] * smooth_w[cc * 64 + k];
      feat_s[i][cc] = s > 0.f ? s : 0.f;
    }
  }
  __syncthreads();
  #pragma unroll
  for (int it = 0; it < 5; ++it) {
    int e = tid + it * 256;
    if (e < 1280) {
      int i = e >> 7, oc = e & 127;
      float s = 0.f;
      for (int k = 0; k < 64; ++k) s += feat_s[i][k] * inc_w[oc * 64 + k];
      out[(bf * 10 + i) * 128 + oc] = s;
    }
  }
  #pragma unroll
  for (int it = 0; it < 3; ++it) {
    int e = tid + it * 256;
    if (e < 640) {
      int i = e >> 6, oc = e & 63;
      float s = 0.f;
      for (int k = 0; k < 64; ++k) s += feat_s[i][k] * pix_w[oc * 64 + k];
      out[20480 + (bf * 10 + i) * 64 + oc] = s;
    }
  }
}

// ---------------- launch ----------------
extern "C" void kernel_launch(void* const* d_in, const int* in_sizes, int n_in,
                              void* d_out, int out_size, void* d_ws, size_t ws_size,
                              hipStream_t stream)
{
  const float* x        = (const float*)d_in[0];
  const float* masks    = (const float*)d_in[1];
  const float* conv1_w  = (const float*)d_in[2];
  const float* conv1_b  = (const float*)d_in[3];
  const float* bn_gamma = (const float*)d_in[4];
  const float* bn_beta  = (const float*)d_in[5];
  const float* bn_mean  = (const float*)d_in[6];
  const float* bn_var   = (const float*)d_in[7];
  const float* off_w    = (const float*)d_in[8];
  const float* off_b    = (const float*)d_in[9];
  const float* mod_w    = (const float*)d_in[10];
  const float* mod_b    = (const float*)d_in[11];
  const float* dcn_w    = (const float*)d_in[12];
  const float* dcn_b    = (const float*)d_in[13];
  const float* smooth_w = (const float*)d_in[14];
  const float* smooth_b = (const float*)d_in[15];
  const float* inc_w    = (const float*)d_in[16];
  const float* pix_w    = (const float*)d_in[17];
  float* out = (float*)d_out;

  if (ws_size < (size_t)WS_NEEDED) return;
  char* ws = (char*)d_ws;
  unsigned short* y1  = (unsigned short*)(ws + OFF_Y1);
  unsigned short* y2  = (unsigned short*)(ws + OFF_Y2);
  unsigned short* xT  = (unsigned short*)(ws + OFF_Y2);   // aliases y2/off/mod/m during conv1 phase
  float* off_t        = (float*)(ws + OFF_OFF);
  float* mod_t        = (float*)(ws + OFF_MOD);
  float* mbuf         = (float*)(ws + OFF_M);
  float* num_part     = (float*)(ws + OFF_NP);
  float* den_part     = (float*)(ws + OFF_DP);
  float* sbn          = (float*)(ws + OFF_SBN);
  float* tbn          = (float*)(ws + OFF_TBN);
  unsigned short* w1  = (unsigned short*)(ws + OFF_W1);
  unsigned short* w2  = (unsigned short*)(ws + OFF_W2);
  unsigned short* w3  = (unsigned short*)(ws + OFF_W3);

  k_prep<<<793, 256, 0, stream>>>(conv1_w, conv1_b, bn_gamma, bn_beta, bn_mean, bn_var,
                                  off_w, mod_w, dcn_w, w1, w2, w3, sbn, tbn);
  for (int pass = 0; pass < 2; ++pass) {
    int n_base = pass * 8;
    k_tr<<<dim3(144, 4, 8), 256, 0, stream>>>(x, xT, n_base);
    k_conv1t<<<dim3(48, 8), 256, 0, stream>>>(xT, w1, sbn, tbn, y1, n_base);
  }
  k_conv2<<<dim3(48, 16), 256, 0, stream>>>(y1, w2, off_b, mod_b, off_t, mod_t);
  k_dcn<<<dim3(96, 16), 256, 0, stream>>>(y1, off_t, mod_t, w3, dcn_b, y2);
  k_resize<<<(16 * 10 * HW + 255) / 256, 256, 0, stream>>>(masks, mbuf);
  k_pool<<<dim3(32, 16), 256, 0, stream>>>(y2, mbuf, num_part, den_part);
  k_head<<<16, 256, 0, stream>>>(num_part, den_part, smooth_w, smooth_b, inc_w, pix_w, out);
}

// Round 4
// 478.428 us; speedup vs baseline: 1.2944x; 1.0164x over previous
//
#include <hip/hip_runtime.h>
#include <hip/hip_bf16.h>

// ---------------- types / helpers ----------------
typedef __attribute__((ext_vector_type(8))) __bf16 bf16x8;
typedef __attribute__((ext_vector_type(4))) float f32x4;
typedef __attribute__((ext_vector_type(2))) float f32x2;
typedef __attribute__((ext_vector_type(4))) unsigned int u32x4;
typedef __attribute__((ext_vector_type(2))) unsigned int u32x2;
typedef __attribute__((ext_vector_type(4))) unsigned short u16x4;
typedef __attribute__((ext_vector_type(8))) unsigned short ushort8;

#define MFMA16(a,b,c) __builtin_amdgcn_mfma_f32_16x16x32_bf16((a),(b),(c),0,0,0)

__device__ __forceinline__ float b2f(unsigned short u) {
  union { unsigned int i; float f; } v; v.i = ((unsigned int)u) << 16; return v.f;
}
__device__ __forceinline__ unsigned short f2b(float f) {
  union { float f; unsigned int u; } v; v.f = f;
  unsigned int u = v.u;
  unsigned int r = (u + 0x7fffu + ((u >> 16) & 1u)) >> 16;  // RTNE
  return (unsigned short)r;
}
__device__ __forceinline__ unsigned short f2h(float f) {
  _Float16 x = (_Float16)f; unsigned short r; __builtin_memcpy(&r, &x, 2); return r;
}
__device__ __forceinline__ float h2f(unsigned short h) {
  _Float16 x; __builtin_memcpy(&x, &h, 2); return (float)x;
}

#define NIMG 16
#define CIN  256
#define CD   64
#define HH   96
#define WW   96
#define HW   (HH*WW)          // 9216

// ---------------- workspace byte offsets ----------------
#define OFF_Y1   (0ll)          // bf16 NHWC 16*9216*64      = 18,874,368 B
#define OFF_Y2   (18874368ll)   // bf16 NHWC same size; ALSO xT (8img NHWC bf16 = 37,748,736 B) during conv1 phase
#define OFF_OFF  (37748736ll)   // f32  16*18*9216           = 10,616,832 B
#define OFF_MOD  (48365568ll)   // f32  16*9*9216            =  5,308,416 B
#define OFF_M    (53673984ll)   // f32  16*10*9216           =  5,898,240 B
#define OFF_NP   OFF_OFF                         // 16*64*10*64*4 = 2,621,440 B (aliases off_t, dead by then)
#define OFF_DP   (OFF_OFF + 2621440ll)           // 16*64*16*4    =     65,536 B
#define OFF_SBN  (59908096ll)   // f32 64
#define OFF_TBN  (59908352ll)   // f32 64
#define OFF_W1   (59908608ll)   // bf16 9*32*64*8 = 147456   =    294,912 B
#define OFF_W2   (60203520ll)   // bf16 9*8*32*8  = 18432    =     36,864 B
#define OFF_W3   (60240384ll)   // bf16 9*8*64*8  = 36864    =     73,728 B
#define WS_NEEDED (60314112ll)

// ---------------- prep: weight repack (frag-order, bf16) + BN fold ----------------
__global__ void k_prep(const float* __restrict__ conv1_w, const float* __restrict__ conv1_b,
                       const float* __restrict__ bn_gamma, const float* __restrict__ bn_beta,
                       const float* __restrict__ bn_mean, const float* __restrict__ bn_var,
                       const float* __restrict__ off_w, const float* __restrict__ mod_w,
                       const float* __restrict__ dcn_w,
                       unsigned short* __restrict__ w1, unsigned short* __restrict__ w2,
                       unsigned short* __restrict__ w3,
                       float* __restrict__ sbn, float* __restrict__ tbn)
{
  int e = blockIdx.x * 256 + threadIdx.x;
  if (e < 147456) {
    int j = e & 7, o = (e >> 3) & 63, cg = (e >> 9) & 31, t = e >> 14;
    w1[e] = f2b(conv1_w[(o * 256 + cg * 8 + j) * 9 + t]);
  } else if (e < 147456 + 18432) {
    int i = e - 147456;
    int j = i & 7, o = (i >> 3) & 31, cg = (i >> 8) & 7, t = i >> 11;
    int ch = cg * 8 + j;
    float v = 0.f;
    if (o < 18)      v = off_w[(o * 64 + ch) * 9 + t];
    else if (o < 27) v = mod_w[((o - 18) * 64 + ch) * 9 + t];
    w2[i] = f2b(v);
  } else if (e < 147456 + 18432 + 36864) {
    int i = e - 147456 - 18432;
    int j = i & 7, o = (i >> 3) & 63, cg = (i >> 9) & 7, t = i >> 12;
    w3[i] = f2b(dcn_w[(o * 64 + cg * 8 + j) * 9 + t]);
  } else {
    int i = e - (147456 + 18432 + 36864);
    if (i < 64) {
      sbn[i] = bn_gamma[i] * rsqrtf(bn_var[i] + 1e-5f);
    } else if (i < 128) {
      int q = i - 64;
      float s = bn_gamma[q] * rsqrtf(bn_var[q] + 1e-5f);
      tbn[q] = (conv1_b[q] - bn_mean[q]) * s + bn_beta[q];
    }
  }
}

// ---------------- transpose x NCHW f32 -> NHWC bf16, 8 images per pass ----------------
__global__ __launch_bounds__(256)
void k_tr(const float* __restrict__ x, unsigned short* __restrict__ xT, int n_base)
{
  __shared__ __align__(16) unsigned short ls[64][68];
  const int tid = threadIdx.x;
  const int p0 = blockIdx.x * 64, c0 = blockIdx.y * 64, nl = blockIdx.z;
  const float* xn = x + (size_t)(n_base + nl) * CIN * HW;

  const int p4 = tid & 15, cb = tid >> 4;
  #pragma unroll
  for (int it = 0; it < 4; ++it) {
    int c = cb + it * 16;
    f32x4 v = *reinterpret_cast<const f32x4*>(xn + (size_t)(c0 + c) * HW + p0 + p4 * 4);
    #pragma unroll
    for (int q = 0; q < 4; ++q) ls[p4 * 4 + q][c] = f2b(v[q]);
  }
  __syncthreads();
  const int cg = tid & 7, pb = tid >> 3;
  #pragma unroll
  for (int it = 0; it < 2; ++it) {
    int p = pb + it * 32;
    u32x2 lo = *reinterpret_cast<const u32x2*>(&ls[p][cg * 8]);
    u32x2 hi = *reinterpret_cast<const u32x2*>(&ls[p][cg * 8 + 4]);
    u32x4 v = {lo[0], lo[1], hi[0], hi[1]};
    *reinterpret_cast<u32x4*>(&xT[((size_t)nl * HW + p0 + p) * CIN + c0 + cg * 8]) = v;
  }
}

// ---------------- conv1 (256->64) + BN + ReLU, NHWC in/out, 1 row/block ----------------
// grid (96 rows, 8 img). wave: (ch-half = wv&1, px-half = wv>>1). acc[2 ch-tiles][3 px-tiles].
__global__ __launch_bounds__(256)
void k_conv1t(const unsigned short* __restrict__ xT, const unsigned short* __restrict__ w1,
              const float* __restrict__ sbn, const float* __restrict__ tbn,
              unsigned short* __restrict__ y1, int n_base)
{
  __shared__ __align__(16) unsigned short sbuf[3 * 98 * 40];   // 23,520 B; reused as ys[96][72]
  #define XS(r,w,c) sbuf[((r) * 98 + (w)) * 40 + (c)]

  const int tid = threadIdx.x;
  const int lane = tid & 63, wv = tid >> 6;
  const int l16 = lane & 15, lg = lane >> 4;
  const int wch = wv & 1, wpx = wv >> 1;
  const int h = blockIdx.x;
  const int nl = blockIdx.y;
  const int n = n_base + nl;
  const unsigned short* xn = xT + (size_t)nl * HW * CIN;

  f32x4 acc[2][3];
  #pragma unroll
  for (int a = 0; a < 2; ++a)
    #pragma unroll
    for (int b = 0; b < 3; ++b) { f32x4 z = {0.f,0.f,0.f,0.f}; acc[a][b] = z; }

  for (int chunk = 0; chunk < 8; ++chunk) {
    const int c0 = chunk * 32;
    __syncthreads();
    // stage 3 rows x 96 w x 32 c (coalesced 16B NHWC)
    #pragma unroll
    for (int it = 0; it < 5; ++it) {
      int idx = tid + it * 256;             // < 1152 = 3r x 96w x 4cg
      if (idx < 1152) {
        int cg = idx & 3, w = (idx >> 2) % 96, r = idx / 384;
        int row = h - 1 + r;
        u32x4 v = {0u,0u,0u,0u};
        if (row >= 0 && row < HH)
          v = *reinterpret_cast<const u32x4*>(&xn[((size_t)row * WW + w) * CIN + c0 + cg * 8]);
        *reinterpret_cast<u32x4*>(&XS(r, w + 1, cg * 8)) = v;
      }
    }
    if (tid < 24) {
      int r = tid >> 3, side = (tid >> 2) & 1, cg = tid & 3;
      u32x4 z = {0u,0u,0u,0u};
      *reinterpret_cast<u32x4*>(&XS(r, side * 97, cg * 8)) = z;
    }
    __syncthreads();
    #pragma unroll
    for (int t = 0; t < 9; ++t) {
      const int ky = t / 3, kx = t % 3;
      bf16x8 a0 = *reinterpret_cast<const bf16x8*>(
          &w1[((t * 32 + chunk * 4 + lg) * 64 + wch * 32 + l16) * 8]);
      bf16x8 a1 = *reinterpret_cast<const bf16x8*>(
          &w1[((t * 32 + chunk * 4 + lg) * 64 + wch * 32 + 16 + l16) * 8]);
      #pragma unroll
      for (int wt = 0; wt < 3; ++wt) {
        bf16x8 b = *reinterpret_cast<const bf16x8*>(&XS(ky, wpx*48 + wt*16 + l16 + kx, lg*8));
        acc[0][wt] = MFMA16(a0, b, acc[0][wt]);
        acc[1][wt] = MFMA16(a1, b, acc[1][wt]);
      }
    }
  }
  // epilogue: BN + ReLU -> LDS transpose -> coalesced NHWC store
  __syncthreads();
  unsigned short* ys = &sbuf[0];              // [96][72]
  #pragma unroll
  for (int ct = 0; ct < 2; ++ct) {
    int o4 = wch * 32 + ct * 16 + lg * 4;
    f32x4 s4 = *reinterpret_cast<const f32x4*>(&sbn[o4]);
    f32x4 t4 = *reinterpret_cast<const f32x4*>(&tbn[o4]);
    #pragma unroll
    for (int wt = 0; wt < 3; ++wt) {
      int p = wpx * 48 + wt * 16 + l16;
      float v0 = acc[ct][wt][0] * s4[0] + t4[0]; v0 = v0 > 0.f ? v0 : 0.f;
      float v1 = acc[ct][wt][1] * s4[1] + t4[1]; v1 = v1 > 0.f ? v1 : 0.f;
      float v2 = acc[ct][wt][2] * s4[2] + t4[2]; v2 = v2 > 0.f ? v2 : 0.f;
      float v3 = acc[ct][wt][3] * s4[3] + t4[3]; v3 = v3 > 0.f ? v3 : 0.f;
      u32x2 d = {(unsigned)f2b(v0) | ((unsigned)f2b(v1) << 16),
                 (unsigned)f2b(v2) | ((unsigned)f2b(v3) << 16)};
      *reinterpret_cast<u32x2*>(&ys[p * 72 + o4]) = d;
    }
  }
  __syncthreads();
  #pragma unroll
  for (int it = 0; it < 3; ++it) {
    int idx = tid + it * 256;                 // 768 = 96p * 8cg
    int cg = idx & 7, p = idx >> 3;
    *reinterpret_cast<u32x4*>(&y1[(((size_t)n * HH + h) * WW + p) * CD + cg * 8]) =
      *reinterpret_cast<const u32x4*>(&ys[p * 72 + cg * 8]);
  }
  #undef XS
}

// ---------------- off/mod conv (64 -> 18+9), MFMA bf16, NHWC input ----------------
__global__ __launch_bounds__(256)
void k_conv2(const unsigned short* __restrict__ y1, const unsigned short* __restrict__ w2,
             const float* __restrict__ off_b, const float* __restrict__ mod_b,
             float* __restrict__ off_o, float* __restrict__ mod_o)
{
  __shared__ __align__(16) unsigned short xs[4][98][40];

  const int tid = threadIdx.x;
  const int lane = tid & 63, wv = tid >> 6;
  const int l16 = lane & 15, lg = lane >> 4;
  const int wrow = wv & 1, wct = wv >> 1;
  const int h0 = blockIdx.x * 2;
  const int n = blockIdx.y;
  const unsigned short* y1n = y1 + (size_t)n * HW * CD;

  f32x4 acc[6];
  #pragma unroll
  for (int b = 0; b < 6; ++b) { f32x4 z = {0.f,0.f,0.f,0.f}; acc[b] = z; }

  #pragma unroll
  for (int chunk = 0; chunk < 2; ++chunk) {
    const int c0 = chunk * 32;
    bf16x8 aR[9];
    #pragma unroll
    for (int t = 0; t < 9; ++t)
      aR[t] = *reinterpret_cast<const bf16x8*>(
          &w2[((t * 8 + chunk * 4 + lg) * 32 + wct * 16 + l16) * 8]);
    __syncthreads();
    #pragma unroll
    for (int it = 0; it < 6; ++it) {
      int idx = tid + it * 256;             // 1536 = 4r x 96w x 4cg
      int cg = idx & 3, w = (idx >> 2) % 96, r = idx / 384;
      int row = h0 - 1 + r;
      u32x4 v = {0u,0u,0u,0u};
      if (row >= 0 && row < HH)
        v = *reinterpret_cast<const u32x4*>(&y1n[((size_t)row * WW + w) * CD + c0 + cg * 8]);
      *reinterpret_cast<u32x4*>(&xs[r][w + 1][cg * 8]) = v;
    }
    if (tid < 32) {
      int r = tid >> 3, side = (tid >> 2) & 1, cg = tid & 3;
      u32x4 z = {0u,0u,0u,0u};
      *reinterpret_cast<u32x4*>(&xs[r][side * 97][cg * 8]) = z;
    }
    __syncthreads();
    #pragma unroll
    for (int t = 0; t < 9; ++t) {
      const int ky = t / 3, kx = t % 3;
      const int r = wrow + ky;
      #pragma unroll
      for (int wt = 0; wt < 6; ++wt) {
        bf16x8 b = *reinterpret_cast<const bf16x8*>(&xs[r][wt*16 + l16 + kx][lg*8]);
        acc[wt] = MFMA16(aR[t], b, acc[wt]);
      }
    }
  }
  const int h = h0 + wrow;
  #pragma unroll
  for (int j = 0; j < 4; ++j) {
    int o = wct * 16 + lg * 4 + j;
    if (o < 18) {
      float bo = off_b[o];
      #pragma unroll
      for (int wt = 0; wt < 6; ++wt)
        off_o[((n * 18 + o) * HH + h) * WW + wt * 16 + l16] = acc[wt][j] + bo;
    } else if (o < 27) {
      int q = o - 18;
      float bo = mod_b[q];
      #pragma unroll
      for (int wt = 0; wt < 6; ++wt) {
        float v = acc[wt][j] + bo;
        mod_o[((n * 9 + q) * HH + h) * WW + wt * 16 + l16] = 2.f / (1.f + expf(-v));
      }
    }
  }
}

// ---------------- deformable conv (DCNv2), NHWC gather, NHWC output ----------------
__global__ __launch_bounds__(256)
void k_dcn(const unsigned short* __restrict__ y1, const float* __restrict__ off_i,
           const float* __restrict__ mod_i, const unsigned short* __restrict__ w3g,
           const float* __restrict__ dcn_b, unsigned short* __restrict__ y2)
{
  __shared__ __align__(16) unsigned short meta[864][8];   // 4xf16 weights + 4xu16 pixel idx
  __shared__ __align__(16) unsigned short Bs[96][72];

  const int tid = threadIdx.x;
  const int lane = tid & 63, wv = tid >> 6;
  const int l16 = lane & 15, lg = lane >> 4;
  const int h = blockIdx.x, n = blockIdx.y;

  #pragma unroll
  for (int it = 0; it < 4; ++it) {
    int e = tid + it * 256;
    if (e < 864) {
      int k = e / 96, p = e % 96;
      float dy = off_i[((n * 18 + 2 * k) * HH + h) * WW + p];
      float dx = off_i[((n * 18 + 2 * k + 1) * HH + h) * WW + p];
      float mw = mod_i[((n * 9 + k) * HH + h) * WW + p];
      float py = (float)(h + k / 3 - 1) + dy;
      float px = (float)(p + k % 3 - 1) + dx;
      float y0f = floorf(py), x0f = floorf(px);
      float wy = py - y0f, wx = px - x0f;
      int iy0 = (int)y0f, ix0 = (int)x0f;
      int iy1 = iy0 + 1, ix1 = ix0 + 1;
      float vy0 = (iy0 >= 0 && iy0 < HH) ? 1.f : 0.f;
      float vy1 = (iy1 >= 0 && iy1 < HH) ? 1.f : 0.f;
      float vx0 = (ix0 >= 0 && ix0 < WW) ? 1.f : 0.f;
      float vx1 = (ix1 >= 0 && ix1 < WW) ? 1.f : 0.f;
      unsigned short m0 = f2h((1.f - wy) * (1.f - wx) * mw * vy0 * vx0);
      unsigned short m1 = f2h((1.f - wy) * wx         * mw * vy0 * vx1);
      unsigned short m2 = f2h(wy         * (1.f - wx) * mw * vy1 * vx0);
      unsigned short m3 = f2h(wy         * wx         * mw * vy1 * vx1);
      int cy0 = iy0 < 0 ? 0 : (iy0 > 95 ? 95 : iy0);
      int cy1 = iy1 < 0 ? 0 : (iy1 > 95 ? 95 : iy1);
      int cx0 = ix0 < 0 ? 0 : (ix0 > 95 ? 95 : ix0);
      int cx1 = ix1 < 0 ? 0 : (ix1 > 95 ? 95 : ix1);
      u32x4 pk = {(unsigned)m0 | ((unsigned)m1 << 16),
                  (unsigned)m2 | ((unsigned)m3 << 16),
                  (unsigned)(cy0 * WW + cx0) | ((unsigned)(cy0 * WW + cx1) << 16),
                  (unsigned)(cy1 * WW + cx0) | ((unsigned)(cy1 * WW + cx1) << 16)};
      *reinterpret_cast<u32x4*>(&meta[e][0]) = pk;
    }
  }
  __syncthreads();

  const unsigned short* y1n = y1 + (size_t)n * HW * CD;
  f32x4 acc[6];
  #pragma unroll
  for (int b = 0; b < 6; ++b) { f32x4 z = {0.f,0.f,0.f,0.f}; acc[b] = z; }

  #pragma unroll
  for (int t = 0; t < 9; ++t) {
    bf16x8 a0 = *reinterpret_cast<const bf16x8*>(
        &w3g[((t * 8 + lg) * 64 + wv * 16 + l16) * 8]);
    bf16x8 a1 = *reinterpret_cast<const bf16x8*>(
        &w3g[((t * 8 + 4 + lg) * 64 + wv * 16 + l16) * 8]);
    #pragma unroll
    for (int it = 0; it < 3; ++it) {
      int idx = tid + it * 256;           // 768 = 96p x 8cg
      int cg = idx & 7, p = idx >> 3;
      u32x4 mk = *reinterpret_cast<const u32x4*>(&meta[t * 96 + p][0]);
      float hw0 = h2f((unsigned short)(mk[0] & 0xffffu));
      float hw1 = h2f((unsigned short)(mk[0] >> 16));
      float hw2 = h2f((unsigned short)(mk[1] & 0xffffu));
      float hw3 = h2f((unsigned short)(mk[1] >> 16));
      int o0 = (int)(mk[2] & 0xffffu) << 6;
      int o1 = (int)(mk[2] >> 16) << 6;
      int o2 = (int)(mk[3] & 0xffffu) << 6;
      int o3 = (int)(mk[3] >> 16) << 6;
      ushort8 g0 = *reinterpret_cast<const ushort8*>(&y1n[o0 + cg * 8]);
      ushort8 g1 = *reinterpret_cast<const ushort8*>(&y1n[o1 + cg * 8]);
      ushort8 g2 = *reinterpret_cast<const ushort8*>(&y1n[o2 + cg * 8]);
      ushort8 g3 = *reinterpret_cast<const ushort8*>(&y1n[o3 + cg * 8]);
      unsigned int wds[4];
      #pragma unroll
      for (int q = 0; q < 4; ++q) {
        float va = hw0*b2f(g0[2*q])   + hw1*b2f(g1[2*q])
                 + hw2*b2f(g2[2*q])   + hw3*b2f(g3[2*q]);
        float vb = hw0*b2f(g0[2*q+1]) + hw1*b2f(g1[2*q+1])
                 + hw2*b2f(g2[2*q+1]) + hw3*b2f(g3[2*q+1]);
        wds[q] = (unsigned int)f2b(va) | ((unsigned int)f2b(vb) << 16);
      }
      u32x4 pk = {wds[0], wds[1], wds[2], wds[3]};
      *reinterpret_cast<u32x4*>(&Bs[p][cg * 8]) = pk;
    }
    __syncthreads();
    #pragma unroll
    for (int wt = 0; wt < 6; ++wt) {
      bf16x8 b0 = *reinterpret_cast<const bf16x8*>(&Bs[wt * 16 + l16][lg * 8]);
      bf16x8 b1 = *reinterpret_cast<const bf16x8*>(&Bs[wt * 16 + l16][32 + lg * 8]);
      acc[wt] = MFMA16(a0, b0, acc[wt]);
      acc[wt] = MFMA16(a1, b1, acc[wt]);
    }
    __syncthreads();
  }

  unsigned short* Bs2 = &Bs[0][0];
  {
    int o4 = wv * 16 + lg * 4;
    f32x4 b4 = *reinterpret_cast<const f32x4*>(&dcn_b[o4]);
    #pragma unroll
    for (int wt = 0; wt < 6; ++wt) {
      int p = wt * 16 + l16;
      u32x2 d = {(unsigned)f2b(acc[wt][0] + b4[0]) | ((unsigned)f2b(acc[wt][1] + b4[1]) << 16),
                 (unsigned)f2b(acc[wt][2] + b4[2]) | ((unsigned)f2b(acc[wt][3] + b4[3]) << 16)};
      *reinterpret_cast<u32x2*>(&Bs2[p * 72 + o4]) = d;
    }
  }
  __syncthreads();
  #pragma unroll
  for (int it = 0; it < 3; ++it) {
    int idx = tid + it * 256;             // 768 = 96p x 8cg
    int cg = idx & 7, p = idx >> 3;
    *reinterpret_cast<u32x4*>(&y2[(((size_t)n * HH + h) * WW + p) * CD + cg * 8]) =
      *reinterpret_cast<const u32x4*>(&Bs2[p * 72 + cg * 8]);
  }
}

// ---------------- mask resize: bilinear x0.5 == 2x2 average, 2 out-px/thread ----------------
__global__ void k_resize(const float* __restrict__ masks, float* __restrict__ m)
{
  int gid = blockIdx.x * 256 + threadIdx.x;
  if (gid >= 16 * 10 * HH * 48) return;
  int ow2 = (gid % 48) * 2;
  int oh = (gid / 48) % HH;
  int r = gid / (48 * HH);
  const float* s = masks + ((size_t)r * 192 + 2 * oh) * 192 + 2 * ow2;
  f32x4 v0 = *reinterpret_cast<const f32x4*>(s);
  f32x4 v1 = *reinterpret_cast<const f32x4*>(s + 192);
  f32x2 o = {0.25f * (v0[0] + v0[1] + v1[0] + v1[1]),
             0.25f * (v0[2] + v0[3] + v1[2] + v1[3])};
  *reinterpret_cast<f32x2*>(&m[(size_t)r * HW + oh * WW + ow2]) = o;
}

// ---------------- pooling partials (f32, packed pairs), NHWC y2 ----------------
// grid (64 seg, 16 bf). per block: 144 pixels, 10 masks x 64 ch.
__global__ __launch_bounds__(256)
void k_pool(const unsigned short* __restrict__ y2, const float* __restrict__ m,
            float* __restrict__ num_part, float* __restrict__ den_part)
{
  __shared__ float ms2[144][12];            // [p][mask], transposed for paired reads
  __shared__ float red[4][10][64];
  __shared__ float den_red[10][16];
  const int tid = threadIdx.x;
  const int seg = blockIdx.x, bf = blockIdx.y;
  const int p0 = seg * 144;

  #pragma unroll
  for (int it = 0; it < 6; ++it) {
    int idx = tid + it * 256;               // < 1440 = 10i x 144p
    if (idx < 1440) {
      int i = idx / 144, p = idx % 144;
      ms2[p][i] = m[(bf * 10 + i) * HW + p0 + p];
    }
  }
  __syncthreads();

  const int c = tid & 63, grp = tid >> 6;
  f32x2 acc2[5];
  #pragma unroll
  for (int i = 0; i < 5; ++i) { f32x2 z = {0.f, 0.f}; acc2[i] = z; }
  const unsigned short* yb = y2 + ((size_t)bf * HW + p0 + grp * 36) * CD + c;
  for (int p = 0; p < 36; ++p) {
    float v = b2f(yb[p * CD]);
    f32x2 vv = {v, v};
    int pp = grp * 36 + p;
    #pragma unroll
    for (int i2 = 0; i2 < 5; ++i2) {
      f32x2 mp = *reinterpret_cast<const f32x2*>(&ms2[pp][i2 * 2]);
      acc2[i2] += vv * mp;                  // v_pk_fma_f32
    }
  }
  #pragma unroll
  for (int i2 = 0; i2 < 5; ++i2) {
    red[grp][2 * i2 + 0][c] = acc2[i2][0];
    red[grp][2 * i2 + 1][c] = acc2[i2][1];
  }
  if (tid < 160) {
    int i = tid >> 4, s16 = tid & 15;
    float s = 0.f;
    for (int k2 = 0; k2 < 9; ++k2) s += ms2[s16 + k2 * 16][i];
    den_red[i][s16] = s;
  }
  __syncthreads();
  #pragma unroll
  for (int it = 0; it < 3; ++it) {
    int e = tid + it * 256;
    if (e < 640) {
      int i = e >> 6, cc = e & 63;
      num_part[((bf * 64 + seg) * 10 + i) * 64 + cc] =
        red[0][i][cc] + red[1][i][cc] + red[2][i][cc] + red[3][i][cc];
    }
  }
  if (tid < 10) {
    float s = 0.f;
    for (int k2 = 0; k2 < 16; ++k2) s += den_red[tid][k2];
    den_part[(bf * 64 + seg) * 16 + tid] = s;
  }
}

// ---------------- head ----------------
__global__ void k_head(const float* __restrict__ num_part, const float* __restrict__ den_part,
                       const float* __restrict__ smooth_w, const float* __restrict__ smooth_b,
                       const float* __restrict__ inc_w, const float* __restrict__ pix_w,
                       float* __restrict__ out)
{
  __shared__ float pool_s[10][64];
  __shared__ float feat_s[10][64];
  const int tid = threadIdx.x;
  const int bf = blockIdx.x;
  #pragma unroll
  for (int it = 0; it < 3; ++it) {
    int e = tid + it * 256;
    if (e < 640) {
      int i = e >> 6, cc = e & 63;
      float nsum = 0.f, dsum = 0.f;
      for (int s = 0; s < 64; ++s) {
        nsum += num_part[((bf * 64 + s) * 10 + i) * 64 + cc];
        dsum += den_part[(bf * 64 + s) * 16 + i];
      }
      pool_s[i][cc] = nsum / (dsum + 1e-6f);
    }
  }
  __syncthreads();
  #pragma unroll
  for (int it = 0; it < 3; ++it) {
    int e = tid + it * 256;
    if (e < 640) {
      int i = e >> 6, cc = e & 63;
      float s = smooth_b[cc];
      for (int k = 0; k < 64; ++k) s += pool_s[i][k] * smooth_w[cc * 64 + k];
      feat_s[i][cc] = s > 0.f ? s : 0.f;
    }
  }
  __syncthreads();
  #pragma unroll
  for (int it = 0; it < 5; ++it) {
    int e = tid + it * 256;
    if (e < 1280) {
      int i = e >> 7, oc = e & 127;
      float s = 0.f;
      for (int k = 0; k < 64; ++k) s += feat_s[i][k] * inc_w[oc * 64 + k];
      out[(bf * 10 + i) * 128 + oc] = s;
    }
  }
  #pragma unroll
  for (int it = 0; it < 3; ++it) {
    int e = tid + it * 256;
    if (e < 640) {
      int i = e >> 6, oc = e & 63;
      float s = 0.f;
      for (int k = 0; k < 64; ++k) s += feat_s[i][k] * pix_w[oc * 64 + k];
      out[20480 + (bf * 10 + i) * 64 + oc] = s;
    }
  }
}

// ---------------- launch ----------------
extern "C" void kernel_launch(void* const* d_in, const int* in_sizes, int n_in,
                              void* d_out, int out_size, void* d_ws, size_t ws_size,
                              hipStream_t stream)
{
  const float* x        = (const float*)d_in[0];
  const float* masks    = (const float*)d_in[1];
  const float* conv1_w  = (const float*)d_in[2];
  const float* conv1_b  = (const float*)d_in[3];
  const float* bn_gamma = (const float*)d_in[4];
  const float* bn_beta  = (const float*)d_in[5];
  const float* bn_mean  = (const float*)d_in[6];
  const float* bn_var   = (const float*)d_in[7];
  const float* off_w    = (const float*)d_in[8];
  const float* off_b    = (const float*)d_in[9];
  const float* mod_w    = (const float*)d_in[10];
  const float* mod_b    = (const float*)d_in[11];
  const float* dcn_w    = (const float*)d_in[12];
  const float* dcn_b    = (const float*)d_in[13];
  const float* smooth_w = (const float*)d_in[14];
  const float* smooth_b = (const float*)d_in[15];
  const float* inc_w    = (const float*)d_in[16];
  const float* pix_w    = (const float*)d_in[17];
  float* out = (float*)d_out;

  if (ws_size < (size_t)WS_NEEDED) return;
  char* ws = (char*)d_ws;
  unsigned short* y1  = (unsigned short*)(ws + OFF_Y1);
  unsigned short* y2  = (unsigned short*)(ws + OFF_Y2);
  unsigned short* xT  = (unsigned short*)(ws + OFF_Y2);   // aliases y2/off/mod/m during conv1 phase
  float* off_t        = (float*)(ws + OFF_OFF);
  float* mod_t        = (float*)(ws + OFF_MOD);
  float* mbuf         = (float*)(ws + OFF_M);
  float* num_part     = (float*)(ws + OFF_NP);
  float* den_part     = (float*)(ws + OFF_DP);
  float* sbn          = (float*)(ws + OFF_SBN);
  float* tbn          = (float*)(ws + OFF_TBN);
  unsigned short* w1  = (unsigned short*)(ws + OFF_W1);
  unsigned short* w2  = (unsigned short*)(ws + OFF_W2);
  unsigned short* w3  = (unsigned short*)(ws + OFF_W3);

  k_prep<<<793, 256, 0, stream>>>(conv1_w, conv1_b, bn_gamma, bn_beta, bn_mean, bn_var,
                                  off_w, mod_w, dcn_w, w1, w2, w3, sbn, tbn);
  for (int pass = 0; pass < 2; ++pass) {
    int n_base = pass * 8;
    k_tr<<<dim3(144, 4, 8), 256, 0, stream>>>(x, xT, n_base);
    k_conv1t<<<dim3(96, 8), 256, 0, stream>>>(xT, w1, sbn, tbn, y1, n_base);
  }
  k_conv2<<<dim3(48, 16), 256, 0, stream>>>(y1, w2, off_b, mod_b, off_t, mod_t);
  k_dcn<<<dim3(96, 16), 256, 0, stream>>>(y1, off_t, mod_t, w3, dcn_b, y2);
  k_resize<<<(16 * 10 * HH * 48 + 255) / 256, 256, 0, stream>>>(masks, mbuf);
  k_pool<<<dim3(64, 16), 256, 0, stream>>>(y2, mbuf, num_part, den_part);
  k_head<<<16, 256, 0, stream>>>(num_part, den_part, smooth_w, smooth_b, inc_w, pix_w, out);
}